// Round 1
// baseline (971.000 us; speedup 1.0000x reference)
//
#include <hip/hip_runtime.h>

#define CDIM 256
#define NSEQ 128
#define HID 1024
#define EPS 1e-5f
#define SCALE 0.17677669529663687f   // 1/sqrt(32)
#define MROWS 32

typedef __attribute__((ext_vector_type(8))) short short8;
typedef __attribute__((ext_vector_type(4))) float f32x4;

static __device__ __forceinline__ unsigned short f2bf(float x) {
    unsigned u = __float_as_uint(x);
    u += 0x7fff + ((u >> 16) & 1);          // RNE
    return (unsigned short)(u >> 16);
}
static __device__ __forceinline__ float bf2f(unsigned short h) {
    return __uint_as_float(((unsigned)h) << 16);
}

// pack two f32 -> two bf16 (RNE), S0 -> low16, S1 -> high16
static __device__ __forceinline__ unsigned cvt_pk(float a, float b) {
    unsigned r;
    asm("v_cvt_pk_bf16_f32 %0, %1, %2" : "=v"(r) : "v"(a), "v"(b));
    return r;
}

// granule swizzle: 16B granule index XOR'd by row hash (row stride = 0 mod 128B)
static __device__ __forceinline__ int swz(int row) { return (row ^ (row >> 2)) & 7; }

// ---------------------------------------------------------------------------
// One launch: split/swizzle all 4 y-path weights into MFMA B-fragment order.
// out[((nt*(K/32)+ks)*64+lane)*8+j] = W[ks*32+(lane>>4)*8+j][nt*16+(lane&15)]
__global__ __launch_bounds__(256) void prep_all(
    const float* __restrict__ We, const float* __restrict__ Woe,
    const float* __restrict__ W1, const float* __restrict__ W2,
    unsigned short* __restrict__ WeH, unsigned short* __restrict__ WeL,
    unsigned short* __restrict__ WoH, unsigned short* __restrict__ W1H,
    unsigned short* __restrict__ W2H) {
    int blk = blockIdx.x;
    const float* W; unsigned short* H; unsigned short* L = nullptr;
    int N, ksBits, base;
    if (blk < 256)       { W = We;  H = WeH; L = WeL; N = 256;  ksBits = 3; base = 0; }
    else if (blk < 512)  { W = Woe; H = WoH; N = 256;  ksBits = 3; base = 256; }
    else if (blk < 1536) { W = W1;  H = W1H; N = 1024; ksBits = 3; base = 512; }
    else                 { W = W2;  H = W2H; N = 256;  ksBits = 5; base = 1536; }
    int idx = (blk - base) * 256 + threadIdx.x;
    int j = idx & 7, lane = (idx >> 3) & 63, rest = idx >> 9;
    int ks = rest & ((1 << ksBits) - 1), nt = rest >> ksBits;
    int n  = nt * 16 + (lane & 15);
    int kk = ks * 32 + ((lane >> 4) << 3) + j;
    float x = W[kk * N + n];
    unsigned short h = f2bf(x);
    H[idx] = h;
    if (L) L[idx] = f2bf(x - bf2f(h));
}

// ---------------------------------------------------------------------------
// Fused LN1 + qkv, 4 rows per block (weight values reused across 4 rows).
__global__ __launch_bounds__(256) void lnqkv_kernel(
    const float* __restrict__ x,
    const float* __restrict__ ln1s, const float* __restrict__ ln1b,
    const float* __restrict__ Wq, const float* __restrict__ bq,
    const float* __restrict__ Wk, const float* __restrict__ bk,
    const float* __restrict__ Wv, const float* __restrict__ bv,
    float* __restrict__ x1,
    float* __restrict__ q, float* __restrict__ k, float* __restrict__ v) {
    __shared__ float sX[4][CDIM];
    __shared__ float sMu[4], sRs[4];
    const int bi0 = blockIdx.x * 4, t = threadIdx.x;
    const int w = t >> 6, lane = t & 63;
    float xv[4];
    #pragma unroll
    for (int r = 0; r < 4; ++r) { xv[r] = x[(bi0 + r) * CDIM + t]; sX[r][t] = xv[r]; }
    __syncthreads();
    {   // wave w does LN stats for row w
        float s = 0.f, ss = 0.f;
        #pragma unroll
        for (int m = 0; m < 4; ++m) { float a = sX[w][lane + 64 * m]; s += a; ss += a * a; }
        #pragma unroll
        for (int off = 32; off; off >>= 1) { s += __shfl_xor(s, off); ss += __shfl_xor(ss, off); }
        if (lane == 0) {
            float mu = s * (1.f / 256.f);
            sMu[w] = mu;
            sRs[w] = rsqrtf(ss * (1.f / 256.f) - mu * mu + EPS);
        }
    }
    __syncthreads();
    #pragma unroll
    for (int r = 0; r < 4; ++r) {
        float xn = (xv[r] - sMu[r]) * sRs[r] * ln1s[t] + ln1b[t];
        sX[r][t] = xn;
        x1[(bi0 + r) * CDIM + t] = xn;
    }
    __syncthreads();
    float aq[4], ak[4], av[4];
    #pragma unroll
    for (int r = 0; r < 4; ++r) { aq[r] = bq[t]; ak[r] = bk[t]; av[r] = bv[t]; }
    #pragma unroll 4
    for (int kk = 0; kk < CDIM; ++kk) {
        float wq = Wq[kk * CDIM + t], wk = Wk[kk * CDIM + t], wv = Wv[kk * CDIM + t];
        #pragma unroll
        for (int r = 0; r < 4; ++r) {
            float xd = sX[r][kk];
            aq[r] += xd * wq; ak[r] += xd * wk; av[r] += xd * wv;
        }
    }
    #pragma unroll
    for (int r = 0; r < 4; ++r) {
        q[(bi0 + r) * CDIM + t] = aq[r];
        k[(bi0 + r) * CDIM + t] = ak[r];
        v[(bi0 + r) * CDIM + t] = av[r];
    }
}

// ---------------------------------------------------------------------------
// bf16 split GEMM step: acc[mt][nt] += A*B over KS k-tiles of 32.
// TERMS==3: Ah*Bh + Al*Bh + Ah*Bl ; TERMS==2: Ah*Bh + Al*Bh (B hi only).
// A planes are [32][LDA] shorts with 16B-granule XOR swizzle by swz(row).
template <int TERMS, int NT, int KS, int LDA>
static __device__ __forceinline__ void gemmN(
    const unsigned short* Ah, const unsigned short* Al,
    const unsigned short* __restrict__ Bh, const unsigned short* __restrict__ Bl,
    int nt0, int ksTotal, int ks0, int lane, f32x4 acc[2][NT])
{
    const int l16 = lane & 15, quad = lane >> 4;
    #pragma unroll 2
    for (int ks = 0; ks < KS; ++ks) {
        short8 bh[NT], bl[NT];
        #pragma unroll
        for (int nt = 0; nt < NT; ++nt) {
            size_t off = ((size_t)((nt0 + nt) * ksTotal + (ks0 + ks)) * 64 + lane) * 8;
            bh[nt] = *(const short8*)(Bh + off);
            if (TERMS == 3) bl[nt] = *(const short8*)(Bl + off);
        }
        #pragma unroll
        for (int mt = 0; mt < 2; ++mt) {
            const int row = mt * 16 + l16;
            const int ao  = row * LDA + (((ks * 4 + quad) ^ swz(row)) << 3);
            short8 ah = *(const short8*)(Ah + ao);
            short8 al = *(const short8*)(Al + ao);
            #pragma unroll
            for (int nt = 0; nt < NT; ++nt) {
                acc[mt][nt] = __builtin_amdgcn_mfma_f32_16x16x32_bf16(ah, bh[nt], acc[mt][nt], 0, 0, 0);
                acc[mt][nt] = __builtin_amdgcn_mfma_f32_16x16x32_bf16(al, bh[nt], acc[mt][nt], 0, 0, 0);
                if (TERMS == 3)
                    acc[mt][nt] = __builtin_amdgcn_mfma_f32_16x16x32_bf16(ah, bl[nt], acc[mt][nt], 0, 0, 0);
            }
        }
    }
}

// cross-wave row-LN for 32 rows, 4 waves; leaves mu in sSum[0..31], rs in sSS[0..31]
static __device__ __forceinline__ void ln_reduce32_4w(
    float pre[2][4][4], float* sSum, float* sSS, int w, int l16, int quad, int tid)
{
    #pragma unroll
    for (int mt = 0; mt < 2; ++mt)
        #pragma unroll
        for (int r = 0; r < 4; ++r) {
            float s = 0.f, ss = 0.f;
            #pragma unroll
            for (int nt = 0; nt < 4; ++nt) {
                float a = pre[mt][nt][r];
                s += a; ss += a * a;
            }
            #pragma unroll
            for (int off = 1; off < 16; off <<= 1) {
                s  += __shfl_xor(s, off);
                ss += __shfl_xor(ss, off);
            }
            if (l16 == 0) {
                int row = mt * 16 + quad * 4 + r;
                sSum[w * 32 + row] = s;
                sSS [w * 32 + row] = ss;
            }
        }
    __syncthreads();
    if (tid < 32) {
        float S = 0.f, SS2 = 0.f;
        #pragma unroll
        for (int ww = 0; ww < 4; ++ww) { S += sSum[ww * 32 + tid]; SS2 += sSS[ww * 32 + tid]; }
        float mu = S * (1.f / 256.f);
        float rs = rsqrtf(SS2 * (1.f / 256.f) - mu * mu + EPS);
        sSum[tid] = mu; sSS[tid] = rs;
    }
    __syncthreads();
}

// ---------------------------------------------------------------------------
// Fused edge pipeline, M=32 rows/block, 256 threads (4 waves, 4 N-tiles each).
// LDS = 50176 B -> 3 blocks/CU. Halves per-CU LDS-read traffic vs 8-wave
// version (each wave still reads full A-tile, but half as many waves), keeps
// per-block weight (L2) traffic constant, and XOR-swizzle kills the epilogue
// ds_write_b16 bank conflicts.
__global__ __launch_bounds__(256, 3) void y_mega(
    const float* __restrict__ y, const float* __restrict__ qg, const float* __restrict__ kg,
    const unsigned short* __restrict__ WeH, const unsigned short* __restrict__ WeL,
    const float* __restrict__ be,
    const unsigned short* __restrict__ WoH, const float* __restrict__ boe,
    const unsigned short* __restrict__ W1H, const float* __restrict__ b1,
    const unsigned short* __restrict__ W2H, const float* __restrict__ b2,
    const float* __restrict__ ln4s, const float* __restrict__ ln4b,
    const float* __restrict__ ln6s, const float* __restrict__ ln6b,
    unsigned short* __restrict__ attn_bf, float* __restrict__ yout)
{
    __shared__ __align__(16) unsigned short sAh[32 * 256], sAl[32 * 256];
    __shared__ __align__(16) unsigned short sHh[32 * 128], sHl[32 * 128];
    __shared__ float sSum[4 * 32], sSS[4 * 32];

    const int tid  = threadIdx.x;
    const int w    = tid >> 6, lane = tid & 63;
    const int l16  = lane & 15, quad = lane >> 4;
    const long long row0 = (long long)blockIdx.x * MROWS;
    const int b  = (int)(row0 >> 14);
    const int i  = (int)((row0 >> 7) & 127);
    const int j0 = (int)(row0 & 127);
    const float* qrow  = qg + ((b << 7) + i) * CDIM;
    const float* kbase = kg + ((b << 7) + j0) * CDIM;
    int c[4];
    #pragma unroll
    for (int nt = 0; nt < 4; ++nt) c[nt] = w * 64 + nt * 16 + l16;

    // ---- stage y tile as hi/lo bf16 planes (swizzled granules) ------------
    {
        const int r  = tid >> 3;                 // 32 rows, 8 threads/row
        const int cb = (tid & 7) * 32;
        const int fr = swz(r);
        const float* src = y + (row0 + r) * CDIM + cb;
        #pragma unroll
        for (int gi = 0; gi < 4; ++gi) {
            float4 v0 = *(const float4*)(src + gi * 8);
            float4 v1 = *(const float4*)(src + gi * 8 + 4);
            float a[8] = {v0.x, v0.y, v0.z, v0.w, v1.x, v1.y, v1.z, v1.w};
            unsigned hw[4], lw[4];
            #pragma unroll
            for (int p = 0; p < 4; ++p) {
                unsigned ph = cvt_pk(a[2 * p], a[2 * p + 1]);
                float r0 = a[2 * p]     - __uint_as_float(ph << 16);
                float r1 = a[2 * p + 1] - __uint_as_float(ph & 0xffff0000u);
                hw[p] = ph;
                lw[p] = cvt_pk(r0, r1);
            }
            const int gs = ((cb >> 3) + gi) ^ fr;
            *(uint4*)&sAh[r * 256 + gs * 8] = *(const uint4*)hw;
            *(uint4*)&sAl[r * 256 + gs * 8] = *(const uint4*)lw;
        }
    }
    __syncthreads();

    const f32x4 zf = {0.f, 0.f, 0.f, 0.f};
    f32x4 acc[2][4];

    // ---- GEMM1 (3-term): e = y@We + be ------------------------------------
    #pragma unroll
    for (int mt = 0; mt < 2; ++mt)
        #pragma unroll
        for (int nt = 0; nt < 4; ++nt) acc[mt][nt] = zf;
    gemmN<3, 4, 8, 256>(sAh, sAl, WeH, WeL, w * 4, 8, 0, lane, acc);

    float qv[4], bev[4];
    #pragma unroll
    for (int nt = 0; nt < 4; ++nt) { qv[nt] = qrow[c[nt]]; bev[nt] = be[c[nt]]; }
    float attnv[2][4][4];
    #pragma unroll
    for (int mt = 0; mt < 2; ++mt)
        #pragma unroll
        for (int r = 0; r < 4; ++r) {
            const int mloc = mt * 16 + quad * 4 + r;
            const float* krow = kbase + mloc * CDIM;
            #pragma unroll
            for (int nt = 0; nt < 4; ++nt) {
                float e = acc[mt][nt][r] + bev[nt];
                attnv[mt][nt][r] = qv[nt] * krow[c[nt]] * SCALE * ((e + 1.f) * e);
            }
        }
    __syncthreads();                       // all waves done reading y planes

    #pragma unroll
    for (int mt = 0; mt < 2; ++mt)
        #pragma unroll
        for (int r = 0; r < 4; ++r) {
            const int mloc = mt * 16 + quad * 4 + r;
            const int fr2  = swz(mloc);
            unsigned short* gout = attn_bf + (row0 + mloc) * CDIM;
            #pragma unroll
            for (int np = 0; np < 4; np += 2) {
                float a0 = attnv[mt][np][r], a1 = attnv[mt][np + 1][r];
                unsigned ph = cvt_pk(a0, a1);
                float r0 = a0 - __uint_as_float(ph << 16);
                float r1 = a1 - __uint_as_float(ph & 0xffff0000u);
                unsigned pl = cvt_pk(r0, r1);
                const int aA = mloc * 256 + (((c[np]     >> 3) ^ fr2) << 3) + (l16 & 7);
                const int aB = mloc * 256 + (((c[np + 1] >> 3) ^ fr2) << 3) + (l16 & 7);
                sAh[aA] = (unsigned short)ph;  sAh[aB] = (unsigned short)(ph >> 16);
                sAl[aA] = (unsigned short)pl;  sAl[aB] = (unsigned short)(pl >> 16);
                gout[c[np]]     = (unsigned short)ph;
                gout[c[np + 1]] = (unsigned short)(ph >> 16);
            }
        }
    __syncthreads();

    // ---- GEMM2 (2-term): edge = attn@Woe + boe ; y2 = LN4(edge + y) -------
    #pragma unroll
    for (int mt = 0; mt < 2; ++mt)
        #pragma unroll
        for (int nt = 0; nt < 4; ++nt) acc[mt][nt] = zf;
    gemmN<2, 4, 8, 256>(sAh, sAl, WoH, nullptr, w * 4, 8, 0, lane, acc);

    float pre[2][4][4];
    float bov[4];
    #pragma unroll
    for (int nt = 0; nt < 4; ++nt) bov[nt] = boe[c[nt]];
    #pragma unroll
    for (int mt = 0; mt < 2; ++mt)
        #pragma unroll
        for (int r = 0; r < 4; ++r) {
            const int mloc = mt * 16 + quad * 4 + r;
            const float* yrow = y + (row0 + mloc) * CDIM;
            #pragma unroll
            for (int nt = 0; nt < 4; ++nt)
                pre[mt][nt][r] = acc[mt][nt][r] + bov[nt] + yrow[c[nt]];
        }
    ln_reduce32_4w(pre, sSum, sSS, w, l16, quad, tid);

    float l4sv[4], l4bv[4];
    #pragma unroll
    for (int nt = 0; nt < 4; ++nt) { l4sv[nt] = ln4s[c[nt]]; l4bv[nt] = ln4b[c[nt]]; }
    float y2v[2][4][4];
    #pragma unroll
    for (int mt = 0; mt < 2; ++mt)
        #pragma unroll
        for (int r = 0; r < 4; ++r) {
            const int mloc = mt * 16 + quad * 4 + r;
            const int fr2  = swz(mloc);
            const float mu = sSum[mloc], rs = sSS[mloc];
            #pragma unroll
            for (int np = 0; np < 4; np += 2) {
                float v0 = (pre[mt][np][r]     - mu) * rs * l4sv[np]     + l4bv[np];
                float v1 = (pre[mt][np + 1][r] - mu) * rs * l4sv[np + 1] + l4bv[np + 1];
                y2v[mt][np][r] = v0; y2v[mt][np + 1][r] = v1;
                unsigned ph = cvt_pk(v0, v1);
                float r0 = v0 - __uint_as_float(ph << 16);
                float r1 = v1 - __uint_as_float(ph & 0xffff0000u);
                unsigned pl = cvt_pk(r0, r1);
                const int aA = mloc * 256 + (((c[np]     >> 3) ^ fr2) << 3) + (l16 & 7);
                const int aB = mloc * 256 + (((c[np + 1] >> 3) ^ fr2) << 3) + (l16 & 7);
                sAh[aA] = (unsigned short)ph;  sAh[aB] = (unsigned short)(ph >> 16);
                sAl[aA] = (unsigned short)pl;  sAl[aB] = (unsigned short)(pl >> 16);
            }
        }
    __syncthreads();                       // A planes now hold y2

    // ---- MLP (2-term), 8 chunks of 128 hidden units -----------------------
    f32x4 out[2][4];
    #pragma unroll
    for (int mt = 0; mt < 2; ++mt)
        #pragma unroll
        for (int nt = 0; nt < 4; ++nt) out[mt][nt] = zf;
    const int hc0 = w * 32 + l16, hc1 = hc0 + 16;   // local hidden cols (0..127)
    for (int ch = 0; ch < 8; ++ch) {
        f32x4 hh[2][2];
        #pragma unroll
        for (int mt = 0; mt < 2; ++mt) { hh[mt][0] = zf; hh[mt][1] = zf; }
        gemmN<2, 2, 8, 256>(sAh, sAl, W1H, nullptr, ch * 8 + w * 2, 8, 0, lane, hh);
        float bb0 = b1[ch * 128 + hc0], bb1 = b1[ch * 128 + hc1];
        __syncthreads();                   // previous fc2 done reading H planes
        #pragma unroll
        for (int mt = 0; mt < 2; ++mt)
            #pragma unroll
            for (int r = 0; r < 4; ++r) {
                const int mloc = mt * 16 + quad * 4 + r;
                const int fr2  = swz(mloc);
                float h0 = fmaxf(hh[mt][0][r] + bb0, 0.f);
                float h1 = fmaxf(hh[mt][1][r] + bb1, 0.f);
                unsigned ph = cvt_pk(h0, h1);
                float r0 = h0 - __uint_as_float(ph << 16);
                float r1 = h1 - __uint_as_float(ph & 0xffff0000u);
                unsigned pl = cvt_pk(r0, r1);
                const int aA = mloc * 128 + (((hc0 >> 3) ^ fr2) << 3) + (hc0 & 7);
                const int aB = mloc * 128 + (((hc1 >> 3) ^ fr2) << 3) + (hc1 & 7);
                sHh[aA] = (unsigned short)ph;  sHh[aB] = (unsigned short)(ph >> 16);
                sHl[aA] = (unsigned short)pl;  sHl[aB] = (unsigned short)(pl >> 16);
            }
        __syncthreads();
        gemmN<2, 4, 4, 128>(sHh, sHl, W2H, nullptr, w * 4, 32, ch * 4, lane, out);
    }

    // ---- epilogue: y_out = LN6(y2 + mlp_out + b2) -------------------------
    float b2v[4];
    #pragma unroll
    for (int nt = 0; nt < 4; ++nt) b2v[nt] = b2[c[nt]];
    #pragma unroll
    for (int mt = 0; mt < 2; ++mt)
        #pragma unroll
        for (int r = 0; r < 4; ++r)
            #pragma unroll
            for (int nt = 0; nt < 4; ++nt)
                pre[mt][nt][r] = y2v[mt][nt][r] + out[mt][nt][r] + b2v[nt];
    ln_reduce32_4w(pre, sSum, sSS, w, l16, quad, tid);

    float l6sv[4], l6bv[4];
    #pragma unroll
    for (int nt = 0; nt < 4; ++nt) { l6sv[nt] = ln6s[c[nt]]; l6bv[nt] = ln6b[c[nt]]; }
    #pragma unroll
    for (int mt = 0; mt < 2; ++mt)
        #pragma unroll
        for (int r = 0; r < 4; ++r) {
            const int mloc = mt * 16 + quad * 4 + r;
            const float mu = sSum[mloc], rs = sSS[mloc];
            float* orow = yout + (row0 + mloc) * CDIM;
            #pragma unroll
            for (int nt = 0; nt < 4; ++nt)
                orow[c[nt]] = (pre[mt][nt][r] - mu) * rs * l6sv[nt] + l6bv[nt];
        }
}

// ---------------------------------------------------------------------------
// softmax over j + weighted v-sum. 2 channels/thread, j-range split in 2 teams.
__global__ __launch_bounds__(256) void softmax_agg(
    const unsigned short* __restrict__ attn, const float* __restrict__ v,
    float* __restrict__ agg) {
    __shared__ float2 sM[2][128], sS[2][128], sO[2][128];
    const int bi = blockIdx.x, t = threadIdx.x;
    const int c2 = t & 127, team = t >> 7, ch = c2 * 2;
    const unsigned short* ap = attn + (size_t)bi * NSEQ * CDIM + ch;
    const float* vp = v + (size_t)(bi >> 7) * NSEQ * CDIM + ch;
    const int jb = team * 64;
    float m0 = -1e30f, m1 = -1e30f;
    #pragma unroll 4
    for (int j = jb; j < jb + 64; ++j) {
        unsigned uu = *(const unsigned*)(ap + (size_t)j * CDIM);
        m0 = fmaxf(m0, bf2f((unsigned short)uu));
        m1 = fmaxf(m1, bf2f((unsigned short)(uu >> 16)));
    }
    sM[team][c2] = make_float2(m0, m1);
    __syncthreads();
    float2 mo = sM[team ^ 1][c2];
    m0 = fmaxf(m0, mo.x); m1 = fmaxf(m1, mo.y);
    float s0 = 0.f, s1 = 0.f, o0 = 0.f, o1 = 0.f;
    #pragma unroll 4
    for (int j = jb; j < jb + 64; ++j) {
        unsigned uu = *(const unsigned*)(ap + (size_t)j * CDIM);
        float e0 = __expf(bf2f((unsigned short)uu) - m0);
        float e1 = __expf(bf2f((unsigned short)(uu >> 16)) - m1);
        float2 vv = *(const float2*)(vp + (size_t)j * CDIM);
        s0 += e0; s1 += e1;
        o0 += e0 * vv.x; o1 += e1 * vv.y;
    }
    sS[team][c2] = make_float2(s0, s1);
    sO[team][c2] = make_float2(o0, o1);
    __syncthreads();
    if (team == 0) {
        float2 s2 = sS[1][c2], o2 = sO[1][c2];
        float r0 = (o0 + o2.x) / (s0 + s2.x);
        float r1 = (o1 + o2.y) / (s1 + s2.y);
        *(float2*)(agg + (size_t)bi * CDIM + ch) = make_float2(r0, r1);
    }
}

// ---------------------------------------------------------------------------
// node path, 4 rows per block (weights reused across rows).
__global__ __launch_bounds__(256) void x_path(
    const float* __restrict__ x1, const float* __restrict__ agg,
    const float* __restrict__ Won, const float* __restrict__ bon,
    const float* __restrict__ ln3s, const float* __restrict__ ln3b,
    const float* __restrict__ w1, const float* __restrict__ b1,
    const float* __restrict__ w2, const float* __restrict__ b2,
    const float* __restrict__ ln5s, const float* __restrict__ ln5b,
    float* __restrict__ xout) {
    __shared__ float sG[4][CDIM];
    __shared__ float sP[4][CDIM];
    __shared__ float sH[4][HID];
    __shared__ float sMu[4], sRs[4];
    const int bi0 = blockIdx.x * 4, t = threadIdx.x;
    const int w = t >> 6, lane = t & 63;
    #pragma unroll
    for (int r = 0; r < 4; ++r) sG[r][t] = agg[(bi0 + r) * CDIM + t];
    __syncthreads();
    float no[4];
    #pragma unroll
    for (int r = 0; r < 4; ++r) no[r] = bon[t];
    #pragma unroll 4
    for (int kk = 0; kk < CDIM; ++kk) {
        float wv = Won[kk * CDIM + t];
        #pragma unroll
        for (int r = 0; r < 4; ++r) no[r] += sG[r][kk] * wv;
    }
    float pre[4];
    #pragma unroll
    for (int r = 0; r < 4; ++r) {
        pre[r] = x1[(bi0 + r) * CDIM + t] + no[r];
        sP[r][t] = pre[r];
    }
    __syncthreads();
    {
        float s = 0.f, ss = 0.f;
        #pragma unroll
        for (int m = 0; m < 4; ++m) { float a = sP[w][lane + 64 * m]; s += a; ss += a * a; }
        #pragma unroll
        for (int off = 32; off; off >>= 1) { s += __shfl_xor(s, off); ss += __shfl_xor(ss, off); }
        if (lane == 0) {
            float mu = s * (1.f / 256.f);
            sMu[w] = mu; sRs[w] = rsqrtf(ss * (1.f / 256.f) - mu * mu + EPS);
        }
    }
    __syncthreads();
    float x2[4];
    #pragma unroll
    for (int r = 0; r < 4; ++r) {
        x2[r] = (pre[r] - sMu[r]) * sRs[r] * ln3s[t] + ln3b[t];
        sP[r][t] = x2[r];
    }
    __syncthreads();
    float h[4][4];
    #pragma unroll
    for (int m = 0; m < 4; ++m) {
        float bb = b1[t + 256 * m];
        #pragma unroll
        for (int r = 0; r < 4; ++r) h[r][m] = bb;
    }
    #pragma unroll 2
    for (int kk = 0; kk < CDIM; ++kk) {
        float wv[4];
        #pragma unroll
        for (int m = 0; m < 4; ++m) wv[m] = w1[kk * HID + t + 256 * m];
        #pragma unroll
        for (int r = 0; r < 4; ++r) {
            float xd = sP[r][kk];
            #pragma unroll
            for (int m = 0; m < 4; ++m) h[r][m] += xd * wv[m];
        }
    }
    #pragma unroll
    for (int r = 0; r < 4; ++r)
        #pragma unroll
        for (int m = 0; m < 4; ++m) sH[r][t + 256 * m] = fmaxf(h[r][m], 0.f);
    __syncthreads();
    float o[4];
    #pragma unroll
    for (int r = 0; r < 4; ++r) o[r] = b2[t];
    #pragma unroll 4
    for (int u = 0; u < HID; ++u) {
        float wv = w2[u * CDIM + t];
        #pragma unroll
        for (int r = 0; r < 4; ++r) o[r] += sH[r][u] * wv;
    }
    float pre2[4];
    #pragma unroll
    for (int r = 0; r < 4; ++r) { pre2[r] = x2[r] + o[r]; sP[r][t] = pre2[r]; }
    __syncthreads();
    {
        float s = 0.f, ss = 0.f;
        #pragma unroll
        for (int m = 0; m < 4; ++m) { float a = sP[w][lane + 64 * m]; s += a; ss += a * a; }
        #pragma unroll
        for (int off = 32; off; off >>= 1) { s += __shfl_xor(s, off); ss += __shfl_xor(ss, off); }
        if (lane == 0) {
            float mu = s * (1.f / 256.f);
            sMu[w] = mu; sRs[w] = rsqrtf(ss * (1.f / 256.f) - mu * mu + EPS);
        }
    }
    __syncthreads();
    #pragma unroll
    for (int r = 0; r < 4; ++r)
        xout[(bi0 + r) * CDIM + t] = (pre2[r] - sMu[r]) * sRs[r] * ln5s[t] + ln5b[t];
}

// ---------------------------------------------------------------------------
extern "C" void kernel_launch(void* const* d_in, const int* in_sizes, int n_in,
                              void* d_out, int out_size, void* d_ws, size_t ws_size,
                              hipStream_t stream) {
    const float* x   = (const float*)d_in[0];
    const float* y   = (const float*)d_in[1];
    const float* Wq  = (const float*)d_in[2];  const float* bq  = (const float*)d_in[3];
    const float* Wk  = (const float*)d_in[4];  const float* bk  = (const float*)d_in[5];
    const float* Wv  = (const float*)d_in[6];  const float* bv  = (const float*)d_in[7];
    const float* We  = (const float*)d_in[8];  const float* be  = (const float*)d_in[9];
    const float* Woe = (const float*)d_in[10]; const float* boe = (const float*)d_in[11];
    const float* Won = (const float*)d_in[12]; const float* bon = (const float*)d_in[13];
    const float* m1w1= (const float*)d_in[14]; const float* m1b1= (const float*)d_in[15];
    const float* m1w2= (const float*)d_in[16]; const float* m1b2= (const float*)d_in[17];
    const float* m2w1= (const float*)d_in[18]; const float* m2b1= (const float*)d_in[19];
    const float* m2w2= (const float*)d_in[20]; const float* m2b2= (const float*)d_in[21];
    const float* ln1s= (const float*)d_in[22]; const float* ln1b= (const float*)d_in[23];
    const float* ln3s= (const float*)d_in[24]; const float* ln3b= (const float*)d_in[25];
    const float* ln4s= (const float*)d_in[26]; const float* ln4b= (const float*)d_in[27];
    const float* ln5s= (const float*)d_in[28]; const float* ln5b= (const float*)d_in[29];
    const float* ln6s= (const float*)d_in[30]; const float* ln6b= (const float*)d_in[31];

    const int BN  = 8 * 128;                 // 1024 node rows
    const long long BNN = 8LL * 128 * 128;   // 131072 edge rows

    float* ws  = (float*)d_ws;
    float* x1  = ws;
    float* q   = x1 + BN * CDIM;
    float* k   = q  + BN * CDIM;
    float* v   = k  + BN * CDIM;
    float* agg = v  + BN * CDIM;
    unsigned short* attn_bf = (unsigned short*)(agg + BN * CDIM);
    unsigned short* WeH = attn_bf + BNN * CDIM;
    unsigned short* WeL = WeH + 65536;
    unsigned short* WoH = WeL + 65536;
    unsigned short* W1H = WoH + 65536;
    unsigned short* W2H = W1H + 262144;

    float* xout = (float*)d_out;
    float* yout = xout + BN * CDIM;

    prep_all<<<2560, 256, 0, stream>>>(We, Woe, m2w1, m2w2, WeH, WeL, WoH, W1H, W2H);
    lnqkv_kernel<<<BN / 4, 256, 0, stream>>>(x, ln1s, ln1b, Wq, bq, Wk, bk, Wv, bv,
                                             x1, q, k, v);
    y_mega<<<(int)(BNN / MROWS), 256, 0, stream>>>(
        y, q, k, WeH, WeL, be, WoH, boe, W1H, m2b1, W2H, m2b2,
        ln4s, ln4b, ln6s, ln6b, attn_bf, yout);
    softmax_agg<<<BN, 256, 0, stream>>>(attn_bf, v, agg);
    x_path<<<BN / 4, 256, 0, stream>>>(x1, agg, Won, bon, ln3s, ln3b,
                                       m1w1, m1b1, m1w2, m1b2, ln5s, ln5b, xout);
}

// Round 2
// 952.971 us; speedup vs baseline: 1.0189x; 1.0189x over previous
//
#include <hip/hip_runtime.h>

#define CDIM 256
#define NSEQ 128
#define HID 1024
#define EPS 1e-5f
#define SCALE 0.17677669529663687f   // 1/sqrt(32)
#define MROWS 32

typedef __attribute__((ext_vector_type(8))) short short8;
typedef __attribute__((ext_vector_type(4))) float f32x4;

static __device__ __forceinline__ unsigned short f2bf(float x) {
    unsigned u = __float_as_uint(x);
    u += 0x7fff + ((u >> 16) & 1);          // RNE
    return (unsigned short)(u >> 16);
}
static __device__ __forceinline__ float bf2f(unsigned short h) {
    return __uint_as_float(((unsigned)h) << 16);
}
// pack two f32 -> two bf16 (RNE), S0 -> low16, S1 -> high16 (HW-verified r1)
static __device__ __forceinline__ unsigned cvt_pk(float a, float b) {
    unsigned r;
    asm("v_cvt_pk_bf16_f32 %0, %1, %2" : "=v"(r) : "v"(a), "v"(b));
    return r;
}
static __device__ __forceinline__ float lo16f(unsigned u) { return __uint_as_float(u << 16); }
static __device__ __forceinline__ float hi16f(unsigned u) { return __uint_as_float(u & 0xffff0000u); }

// 16B-granule XOR swizzle (row stride 512 B = 0 mod 128 B)
static __device__ __forceinline__ int swz(int row) { return (row ^ (row >> 2)) & 7; }

// ---------------------------------------------------------------------------
// One launch: split/swizzle all 4 y-path weights into MFMA B-fragment order.
__global__ __launch_bounds__(256) void prep_all(
    const float* __restrict__ We, const float* __restrict__ Woe,
    const float* __restrict__ W1, const float* __restrict__ W2,
    unsigned short* __restrict__ WeH, unsigned short* __restrict__ WeL,
    unsigned short* __restrict__ WoH, unsigned short* __restrict__ W1H,
    unsigned short* __restrict__ W2H) {
    int blk = blockIdx.x;
    const float* W; unsigned short* H; unsigned short* L = nullptr;
    int N, ksBits, base;
    if (blk < 256)       { W = We;  H = WeH; L = WeL; N = 256;  ksBits = 3; base = 0; }
    else if (blk < 512)  { W = Woe; H = WoH; N = 256;  ksBits = 3; base = 256; }
    else if (blk < 1536) { W = W1;  H = W1H; N = 1024; ksBits = 3; base = 512; }
    else                 { W = W2;  H = W2H; N = 256;  ksBits = 5; base = 1536; }
    int idx = (blk - base) * 256 + threadIdx.x;
    int j = idx & 7, lane = (idx >> 3) & 63, rest = idx >> 9;
    int ks = rest & ((1 << ksBits) - 1), nt = rest >> ksBits;
    int n  = nt * 16 + (lane & 15);
    int kk = ks * 32 + ((lane >> 4) << 3) + j;
    float x = W[kk * N + n];
    unsigned short h = f2bf(x);
    H[idx] = h;
    if (L) L[idx] = f2bf(x - bf2f(h));
}

// ---------------------------------------------------------------------------
// Fused LN1 + qkv, 4 rows per block (weight values reused across 4 rows).
__global__ __launch_bounds__(256) void lnqkv_kernel(
    const float* __restrict__ x,
    const float* __restrict__ ln1s, const float* __restrict__ ln1b,
    const float* __restrict__ Wq, const float* __restrict__ bq,
    const float* __restrict__ Wk, const float* __restrict__ bk,
    const float* __restrict__ Wv, const float* __restrict__ bv,
    float* __restrict__ x1,
    float* __restrict__ q, float* __restrict__ k, float* __restrict__ v) {
    __shared__ float sX[4][CDIM];
    __shared__ float sMu[4], sRs[4];
    const int bi0 = blockIdx.x * 4, t = threadIdx.x;
    const int w = t >> 6, lane = t & 63;
    float xv[4];
    #pragma unroll
    for (int r = 0; r < 4; ++r) { xv[r] = x[(bi0 + r) * CDIM + t]; sX[r][t] = xv[r]; }
    __syncthreads();
    {
        float s = 0.f, ss = 0.f;
        #pragma unroll
        for (int m = 0; m < 4; ++m) { float a = sX[w][lane + 64 * m]; s += a; ss += a * a; }
        #pragma unroll
        for (int off = 32; off; off >>= 1) { s += __shfl_xor(s, off); ss += __shfl_xor(ss, off); }
        if (lane == 0) {
            float mu = s * (1.f / 256.f);
            sMu[w] = mu;
            sRs[w] = rsqrtf(ss * (1.f / 256.f) - mu * mu + EPS);
        }
    }
    __syncthreads();
    #pragma unroll
    for (int r = 0; r < 4; ++r) {
        float xn = (xv[r] - sMu[r]) * sRs[r] * ln1s[t] + ln1b[t];
        sX[r][t] = xn;
        x1[(bi0 + r) * CDIM + t] = xn;
    }
    __syncthreads();
    float aq[4], ak[4], av[4];
    #pragma unroll
    for (int r = 0; r < 4; ++r) { aq[r] = bq[t]; ak[r] = bk[t]; av[r] = bv[t]; }
    #pragma unroll 4
    for (int kk = 0; kk < CDIM; ++kk) {
        float wq = Wq[kk * CDIM + t], wk = Wk[kk * CDIM + t], wv = Wv[kk * CDIM + t];
        #pragma unroll
        for (int r = 0; r < 4; ++r) {
            float xd = sX[r][kk];
            aq[r] += xd * wq; ak[r] += xd * wk; av[r] += xd * wv;
        }
    }
    #pragma unroll
    for (int r = 0; r < 4; ++r) {
        q[(bi0 + r) * CDIM + t] = aq[r];
        k[(bi0 + r) * CDIM + t] = ak[r];
        v[(bi0 + r) * CDIM + t] = av[r];
    }
}

// ---------------------------------------------------------------------------
// bf16 split GEMM step over K=256: acc[mt][nt] += A*B.
// A planes: [32][256] shorts, 16B granules XOR-swizzled by swz(row).
template <int TERMS>
static __device__ __forceinline__ void gemmN(
    const unsigned short* Ah, const unsigned short* Al,
    const unsigned short* __restrict__ Bh, const unsigned short* __restrict__ Bl,
    int nt0, int ksTotal, int ks0, int lane, f32x4 acc[2][2])
{
    const int l16 = lane & 15, quad = lane >> 4;
    #pragma unroll 2
    for (int ks = 0; ks < 8; ++ks) {
        short8 bh[2], bl[2];
        #pragma unroll
        for (int nt = 0; nt < 2; ++nt) {
            size_t off = ((size_t)((nt0 + nt) * ksTotal + (ks0 + ks)) * 64 + lane) * 8;
            bh[nt] = *(const short8*)(Bh + off);
            if (TERMS == 3) bl[nt] = *(const short8*)(Bl + off);
        }
        #pragma unroll
        for (int mt = 0; mt < 2; ++mt) {
            const int row = mt * 16 + l16;
            const int ao  = row * 256 + (((ks * 4 + quad) ^ swz(row)) << 3);
            short8 ah = *(const short8*)(Ah + ao);
            short8 al = *(const short8*)(Al + ao);
            #pragma unroll
            for (int nt = 0; nt < 2; ++nt) {
                acc[mt][nt] = __builtin_amdgcn_mfma_f32_16x16x32_bf16(ah, bh[nt], acc[mt][nt], 0, 0, 0);
                acc[mt][nt] = __builtin_amdgcn_mfma_f32_16x16x32_bf16(al, bh[nt], acc[mt][nt], 0, 0, 0);
                if (TERMS == 3)
                    acc[mt][nt] = __builtin_amdgcn_mfma_f32_16x16x32_bf16(ah, bl[nt], acc[mt][nt], 0, 0, 0);
            }
        }
    }
}

// cross-wave row-LN for 32 rows (8 waves); mu in sSum[0..31], rs in sSS[0..31]
static __device__ __forceinline__ void ln_reduce32(
    float pre[2][2][4], float* sSum, float* sSS, int w, int l16, int quad, int tid)
{
    #pragma unroll
    for (int mt = 0; mt < 2; ++mt)
        #pragma unroll
        for (int r = 0; r < 4; ++r) {
            float s  = pre[mt][0][r] + pre[mt][1][r];
            float ss = pre[mt][0][r] * pre[mt][0][r] + pre[mt][1][r] * pre[mt][1][r];
            #pragma unroll
            for (int off = 1; off < 16; off <<= 1) {
                s  += __shfl_xor(s, off);
                ss += __shfl_xor(ss, off);
            }
            if (l16 == 0) {
                int row = mt * 16 + quad * 4 + r;
                sSum[w * 32 + row] = s;
                sSS [w * 32 + row] = ss;
            }
        }
    __syncthreads();
    if (tid < 32) {
        float S = 0.f, SS2 = 0.f;
        #pragma unroll
        for (int ww = 0; ww < 8; ++ww) { S += sSum[ww * 32 + tid]; SS2 += sSS[ww * 32 + tid]; }
        float mu = S * (1.f / 256.f);
        float rs = rsqrtf(SS2 * (1.f / 256.f) - mu * mu + EPS);
        sSum[tid] = mu; sSS[tid] = rs;
    }
    __syncthreads();
}

// pair-packed plane store: lanes (l, l^1) own channels (p, p+1), p = c&~1.
// Both lanes build the hi-pack ph; even lane stores ph to hi plane as b32,
// odd lane builds+stores the residual pack pl to lo plane as b32.
// Returns pack to store (ph on even lanes, pl on odd lanes).
static __device__ __forceinline__ unsigned pair_pack(float v, bool odd, unsigned* ph_out) {
    float part = __shfl_xor(v, 1);
    float lo = odd ? part : v;
    float hi = odd ? v : part;
    unsigned ph = cvt_pk(lo, hi);
    *ph_out = ph;
    if (odd) {
        float rlo = lo - lo16f(ph);
        float rhi = hi - hi16f(ph);
        return cvt_pk(rlo, rhi);
    }
    return ph;
}
static __device__ __forceinline__ void plane_store(
    unsigned short* Hp, unsigned short* Lp, int row, int c, unsigned pk, bool odd) {
    const int p = c & ~1;
    const int idx = row * 256 + ((((p >> 3) ^ swz(row)) << 3)) + (p & 7);
    if (!odd) *(unsigned*)&Hp[idx] = pk;
    else      *(unsigned*)&Lp[idx] = pk;
}

// ---------------------------------------------------------------------------
// Fused edge pipeline, M=32 rows/block, 512 threads (8 waves), 66 KB LDS
// -> 2 blocks/CU. Epilogues use pair-packed b32 stores (conflict-free under
// the granule swizzle) instead of scalar b16 stores.
__global__ __launch_bounds__(512, 4) void y_mega(
    const float* __restrict__ y, const float* __restrict__ qg, const float* __restrict__ kg,
    const unsigned short* __restrict__ WeH, const unsigned short* __restrict__ WeL,
    const float* __restrict__ be,
    const unsigned short* __restrict__ WoH, const float* __restrict__ boe,
    const unsigned short* __restrict__ W1H, const float* __restrict__ b1,
    const unsigned short* __restrict__ W2H, const float* __restrict__ b2,
    const float* __restrict__ ln4s, const float* __restrict__ ln4b,
    const float* __restrict__ ln6s, const float* __restrict__ ln6b,
    unsigned short* __restrict__ attn_bf, float* __restrict__ yout)
{
    __shared__ __align__(16) unsigned short sAh[32 * 256], sAl[32 * 256];
    __shared__ __align__(16) unsigned short sHh[32 * 256], sHl[32 * 256];
    __shared__ float sSum[8 * 32], sSS[8 * 32];

    const int tid  = threadIdx.x;
    const int w    = tid >> 6, lane = tid & 63;
    const int l16  = lane & 15, quad = lane >> 4;
    const bool odd = (l16 & 1) != 0;
    const long long row0 = (long long)blockIdx.x * MROWS;
    const int b  = (int)(row0 >> 14);
    const int i  = (int)((row0 >> 7) & 127);
    const int j0 = (int)(row0 & 127);
    const float* qrow  = qg + ((b << 7) + i) * CDIM;
    const float* kbase = kg + ((b << 7) + j0) * CDIM;
    const int c0 = w * 32 + l16, c1 = c0 + 16;

    // ---- stage y tile as hi/lo bf16 planes (swizzled granules) ------------
    {
        const int r  = tid >> 4;                 // 32 rows, 16 threads/row
        const int cc = (tid & 15) * 16;
        const int fr = swz(r);
        const float* src = y + (row0 + r) * CDIM + cc;
        #pragma unroll
        for (int e = 0; e < 16; e += 8) {
            float4 v0 = *(const float4*)(src + e);
            float4 v1 = *(const float4*)(src + e + 4);
            unsigned h0 = cvt_pk(v0.x, v0.y);
            unsigned h1 = cvt_pk(v0.z, v0.w);
            unsigned h2 = cvt_pk(v1.x, v1.y);
            unsigned h3 = cvt_pk(v1.z, v1.w);
            unsigned L0 = cvt_pk(v0.x - lo16f(h0), v0.y - hi16f(h0));
            unsigned L1 = cvt_pk(v0.z - lo16f(h1), v0.w - hi16f(h1));
            unsigned L2 = cvt_pk(v1.x - lo16f(h2), v1.y - hi16f(h2));
            unsigned L3 = cvt_pk(v1.z - lo16f(h3), v1.w - hi16f(h3));
            const int gs = (((cc + e) >> 3) ^ fr);
            uint4 hv; hv.x = h0; hv.y = h1; hv.z = h2; hv.w = h3;
            uint4 lv; lv.x = L0; lv.y = L1; lv.z = L2; lv.w = L3;
            *(uint4*)&sAh[r * 256 + gs * 8] = hv;
            *(uint4*)&sAl[r * 256 + gs * 8] = lv;
        }
    }
    __syncthreads();

    f32x4 acc[2][2];
    const f32x4 zf = {0.f, 0.f, 0.f, 0.f};

    // ---- GEMM1 (3-term): e = y@We + be ------------------------------------
    #pragma unroll
    for (int mt = 0; mt < 2; ++mt) { acc[mt][0] = zf; acc[mt][1] = zf; }
    gemmN<3>(sAh, sAl, WeH, WeL, w * 2, 8, 0, lane, acc);

    float q0 = qrow[c0], q1 = qrow[c1];
    float be0 = be[c0], be1 = be[c1];
    unsigned pk1[2][2][4];
    #pragma unroll
    for (int mt = 0; mt < 2; ++mt)
        #pragma unroll
        for (int r = 0; r < 4; ++r) {
            const int mloc = mt * 16 + quad * 4 + r;
            const float* krow = kbase + mloc * CDIM;
            unsigned short* gout = attn_bf + (row0 + mloc) * CDIM;
            #pragma unroll
            for (int nt = 0; nt < 2; ++nt) {
                const int c = (nt == 0) ? c0 : c1;
                float e = acc[mt][nt][r] + ((nt == 0) ? be0 : be1);
                float a = ((nt == 0) ? q0 : q1) * krow[c] * SCALE * ((e + 1.f) * e);
                unsigned ph;
                pk1[mt][nt][r] = pair_pack(a, odd, &ph);
                if (!odd) *(unsigned*)&gout[c & ~1] = ph;
            }
        }
    __syncthreads();                       // all waves done reading y planes

    #pragma unroll
    for (int mt = 0; mt < 2; ++mt)
        #pragma unroll
        for (int r = 0; r < 4; ++r) {
            const int mloc = mt * 16 + quad * 4 + r;
            plane_store(sAh, sAl, mloc, c0, pk1[mt][0][r], odd);
            plane_store(sAh, sAl, mloc, c1, pk1[mt][1][r], odd);
        }
    __syncthreads();

    // ---- GEMM2 (2-term): edge = attn@Woe + boe ; y2 = LN4(edge + y) -------
    #pragma unroll
    for (int mt = 0; mt < 2; ++mt) { acc[mt][0] = zf; acc[mt][1] = zf; }
    gemmN<2>(sAh, sAl, WoH, nullptr, w * 2, 8, 0, lane, acc);

    float pre[2][2][4];
    float bo0 = boe[c0], bo1 = boe[c1];
    #pragma unroll
    for (int mt = 0; mt < 2; ++mt)
        #pragma unroll
        for (int r = 0; r < 4; ++r) {
            const int mloc = mt * 16 + quad * 4 + r;
            pre[mt][0][r] = acc[mt][0][r] + bo0 + y[(row0 + mloc) * CDIM + c0];
            pre[mt][1][r] = acc[mt][1][r] + bo1 + y[(row0 + mloc) * CDIM + c1];
        }
    ln_reduce32(pre, sSum, sSS, w, l16, quad, tid);

    float l4s0 = ln4s[c0], l4b0 = ln4b[c0], l4s1 = ln4s[c1], l4b1 = ln4b[c1];
    float y2v[2][2][4];
    #pragma unroll
    for (int mt = 0; mt < 2; ++mt)
        #pragma unroll
        for (int r = 0; r < 4; ++r) {
            const int mloc = mt * 16 + quad * 4 + r;
            const float mu = sSum[mloc], rs = sSS[mloc];
            float v0 = (pre[mt][0][r] - mu) * rs * l4s0 + l4b0;
            float v1 = (pre[mt][1][r] - mu) * rs * l4s1 + l4b1;
            y2v[mt][0][r] = v0; y2v[mt][1][r] = v1;
            unsigned ph;
            unsigned p0 = pair_pack(v0, odd, &ph);
            unsigned p1 = pair_pack(v1, odd, &ph);
            plane_store(sAh, sAl, mloc, c0, p0, odd);
            plane_store(sAh, sAl, mloc, c1, p1, odd);
        }
    __syncthreads();                       // A planes now hold y2

    // ---- MLP (2-term), 4 quarters of 256 hidden units ---------------------
    f32x4 out[2][2];
    #pragma unroll
    for (int mt = 0; mt < 2; ++mt) { out[mt][0] = zf; out[mt][1] = zf; }
    for (int qq = 0; qq < 4; ++qq) {
        f32x4 hh[2][2];
        #pragma unroll
        for (int mt = 0; mt < 2; ++mt) { hh[mt][0] = zf; hh[mt][1] = zf; }
        gemmN<2>(sAh, sAl, W1H, nullptr, qq * 16 + w * 2, 8, 0, lane, hh);
        float bb0 = b1[qq * 256 + c0], bb1 = b1[qq * 256 + c1];
        __syncthreads();                   // previous fc2 done reading H planes
        #pragma unroll
        for (int mt = 0; mt < 2; ++mt)
            #pragma unroll
            for (int r = 0; r < 4; ++r) {
                const int mloc = mt * 16 + quad * 4 + r;
                float h0 = fmaxf(hh[mt][0][r] + bb0, 0.f);
                float h1 = fmaxf(hh[mt][1][r] + bb1, 0.f);
                unsigned ph;
                unsigned p0 = pair_pack(h0, odd, &ph);
                unsigned p1 = pair_pack(h1, odd, &ph);
                plane_store(sHh, sHl, mloc, c0, p0, odd);
                plane_store(sHh, sHl, mloc, c1, p1, odd);
            }
        __syncthreads();
        gemmN<2>(sHh, sHl, W2H, nullptr, w * 2, 32, qq * 8, lane, out);
    }

    // ---- epilogue: y_out = LN6(y2 + mlp_out + b2) -------------------------
    float b20 = b2[c0], b21 = b2[c1];
    #pragma unroll
    for (int mt = 0; mt < 2; ++mt)
        #pragma unroll
        for (int r = 0; r < 4; ++r) {
            pre[mt][0][r] = y2v[mt][0][r] + out[mt][0][r] + b20;
            pre[mt][1][r] = y2v[mt][1][r] + out[mt][1][r] + b21;
        }
    ln_reduce32(pre, sSum, sSS, w, l16, quad, tid);

    float l6s0 = ln6s[c0], l6b0 = ln6b[c0], l6s1 = ln6s[c1], l6b1 = ln6b[c1];
    #pragma unroll
    for (int mt = 0; mt < 2; ++mt)
        #pragma unroll
        for (int r = 0; r < 4; ++r) {
            const int mloc = mt * 16 + quad * 4 + r;
            const float mu = sSum[mloc], rs = sSS[mloc];
            yout[(row0 + mloc) * CDIM + c0] = (pre[mt][0][r] - mu) * rs * l6s0 + l6b0;
            yout[(row0 + mloc) * CDIM + c1] = (pre[mt][1][r] - mu) * rs * l6s1 + l6b1;
        }
}

// ---------------------------------------------------------------------------
// softmax over j + weighted v-sum. 2 channels/thread, j-range split in 2 teams.
__global__ __launch_bounds__(256) void softmax_agg(
    const unsigned short* __restrict__ attn, const float* __restrict__ v,
    float* __restrict__ agg) {
    __shared__ float2 sM[2][128], sS[2][128], sO[2][128];
    const int bi = blockIdx.x, t = threadIdx.x;
    const int c2 = t & 127, team = t >> 7, ch = c2 * 2;
    const unsigned short* ap = attn + (size_t)bi * NSEQ * CDIM + ch;
    const float* vp = v + (size_t)(bi >> 7) * NSEQ * CDIM + ch;
    const int jb = team * 64;
    float m0 = -1e30f, m1 = -1e30f;
    #pragma unroll 4
    for (int j = jb; j < jb + 64; ++j) {
        unsigned uu = *(const unsigned*)(ap + (size_t)j * CDIM);
        m0 = fmaxf(m0, bf2f((unsigned short)uu));
        m1 = fmaxf(m1, bf2f((unsigned short)(uu >> 16)));
    }
    sM[team][c2] = make_float2(m0, m1);
    __syncthreads();
    float2 mo = sM[team ^ 1][c2];
    m0 = fmaxf(m0, mo.x); m1 = fmaxf(m1, mo.y);
    float s0 = 0.f, s1 = 0.f, o0 = 0.f, o1 = 0.f;
    #pragma unroll 4
    for (int j = jb; j < jb + 64; ++j) {
        unsigned uu = *(const unsigned*)(ap + (size_t)j * CDIM);
        float e0 = __expf(bf2f((unsigned short)uu) - m0);
        float e1 = __expf(bf2f((unsigned short)(uu >> 16)) - m1);
        float2 vv = *(const float2*)(vp + (size_t)j * CDIM);
        s0 += e0; s1 += e1;
        o0 += e0 * vv.x; o1 += e1 * vv.y;
    }
    sS[team][c2] = make_float2(s0, s1);
    sO[team][c2] = make_float2(o0, o1);
    __syncthreads();
    if (team == 0) {
        float2 s2 = sS[1][c2], o2 = sO[1][c2];
        float r0 = (o0 + o2.x) / (s0 + s2.x);
        float r1 = (o1 + o2.y) / (s1 + s2.y);
        *(float2*)(agg + (size_t)bi * CDIM + ch) = make_float2(r0, r1);
    }
}

// ---------------------------------------------------------------------------
// node path, 4 rows per block (weights reused across rows).
__global__ __launch_bounds__(256) void x_path(
    const float* __restrict__ x1, const float* __restrict__ agg,
    const float* __restrict__ Won, const float* __restrict__ bon,
    const float* __restrict__ ln3s, const float* __restrict__ ln3b,
    const float* __restrict__ w1, const float* __restrict__ b1,
    const float* __restrict__ w2, const float* __restrict__ b2,
    const float* __restrict__ ln5s, const float* __restrict__ ln5b,
    float* __restrict__ xout) {
    __shared__ float sG[4][CDIM];
    __shared__ float sP[4][CDIM];
    __shared__ float sH[4][HID];
    __shared__ float sMu[4], sRs[4];
    const int bi0 = blockIdx.x * 4, t = threadIdx.x;
    const int w = t >> 6, lane = t & 63;
    #pragma unroll
    for (int r = 0; r < 4; ++r) sG[r][t] = agg[(bi0 + r) * CDIM + t];
    __syncthreads();
    float no[4];
    #pragma unroll
    for (int r = 0; r < 4; ++r) no[r] = bon[t];
    #pragma unroll 4
    for (int kk = 0; kk < CDIM; ++kk) {
        float wv = Won[kk * CDIM + t];
        #pragma unroll
        for (int r = 0; r < 4; ++r) no[r] += sG[r][kk] * wv;
    }
    float pre[4];
    #pragma unroll
    for (int r = 0; r < 4; ++r) {
        pre[r] = x1[(bi0 + r) * CDIM + t] + no[r];
        sP[r][t] = pre[r];
    }
    __syncthreads();
    {
        float s = 0.f, ss = 0.f;
        #pragma unroll
        for (int m = 0; m < 4; ++m) { float a = sP[w][lane + 64 * m]; s += a; ss += a * a; }
        #pragma unroll
        for (int off = 32; off; off >>= 1) { s += __shfl_xor(s, off); ss += __shfl_xor(ss, off); }
        if (lane == 0) {
            float mu = s * (1.f / 256.f);
            sMu[w] = mu; sRs[w] = rsqrtf(ss * (1.f / 256.f) - mu * mu + EPS);
        }
    }
    __syncthreads();
    float x2[4];
    #pragma unroll
    for (int r = 0; r < 4; ++r) {
        x2[r] = (pre[r] - sMu[r]) * sRs[r] * ln3s[t] + ln3b[t];
        sP[r][t] = x2[r];
    }
    __syncthreads();
    float h[4][4];
    #pragma unroll
    for (int m = 0; m < 4; ++m) {
        float bb = b1[t + 256 * m];
        #pragma unroll
        for (int r = 0; r < 4; ++r) h[r][m] = bb;
    }
    #pragma unroll 2
    for (int kk = 0; kk < CDIM; ++kk) {
        float wv[4];
        #pragma unroll
        for (int m = 0; m < 4; ++m) wv[m] = w1[kk * HID + t + 256 * m];
        #pragma unroll
        for (int r = 0; r < 4; ++r) {
            float xd = sP[r][kk];
            #pragma unroll
            for (int m = 0; m < 4; ++m) h[r][m] += xd * wv[m];
        }
    }
    #pragma unroll
    for (int r = 0; r < 4; ++r)
        #pragma unroll
        for (int m = 0; m < 4; ++m) sH[r][t + 256 * m] = fmaxf(h[r][m], 0.f);
    __syncthreads();
    float o[4];
    #pragma unroll
    for (int r = 0; r < 4; ++r) o[r] = b2[t];
    #pragma unroll 4
    for (int u = 0; u < HID; ++u) {
        float wv = w2[u * CDIM + t];
        #pragma unroll
        for (int r = 0; r < 4; ++r) o[r] += sH[r][u] * wv;
    }
    float pre2[4];
    #pragma unroll
    for (int r = 0; r < 4; ++r) { pre2[r] = x2[r] + o[r]; sP[r][t] = pre2[r]; }
    __syncthreads();
    {
        float s = 0.f, ss = 0.f;
        #pragma unroll
        for (int m = 0; m < 4; ++m) { float a = sP[w][lane + 64 * m]; s += a; ss += a * a; }
        #pragma unroll
        for (int off = 32; off; off >>= 1) { s += __shfl_xor(s, off); ss += __shfl_xor(ss, off); }
        if (lane == 0) {
            float mu = s * (1.f / 256.f);
            sMu[w] = mu; sRs[w] = rsqrtf(ss * (1.f / 256.f) - mu * mu + EPS);
        }
    }
    __syncthreads();
    #pragma unroll
    for (int r = 0; r < 4; ++r)
        xout[(bi0 + r) * CDIM + t] = (pre2[r] - sMu[r]) * sRs[r] * ln5s[t] + ln5b[t];
}

// ---------------------------------------------------------------------------
extern "C" void kernel_launch(void* const* d_in, const int* in_sizes, int n_in,
                              void* d_out, int out_size, void* d_ws, size_t ws_size,
                              hipStream_t stream) {
    const float* x   = (const float*)d_in[0];
    const float* y   = (const float*)d_in[1];
    const float* Wq  = (const float*)d_in[2];  const float* bq  = (const float*)d_in[3];
    const float* Wk  = (const float*)d_in[4];  const float* bk  = (const float*)d_in[5];
    const float* Wv  = (const float*)d_in[6];  const float* bv  = (const float*)d_in[7];
    const float* We  = (const float*)d_in[8];  const float* be  = (const float*)d_in[9];
    const float* Woe = (const float*)d_in[10]; const float* boe = (const float*)d_in[11];
    const float* Won = (const float*)d_in[12]; const float* bon = (const float*)d_in[13];
    const float* m1w1= (const float*)d_in[14]; const float* m1b1= (const float*)d_in[15];
    const float* m1w2= (const float*)d_in[16]; const float* m1b2= (const float*)d_in[17];
    const float* m2w1= (const float*)d_in[18]; const float* m2b1= (const float*)d_in[19];
    const float* m2w2= (const float*)d_in[20]; const float* m2b2= (const float*)d_in[21];
    const float* ln1s= (const float*)d_in[22]; const float* ln1b= (const float*)d_in[23];
    const float* ln3s= (const float*)d_in[24]; const float* ln3b= (const float*)d_in[25];
    const float* ln4s= (const float*)d_in[26]; const float* ln4b= (const float*)d_in[27];
    const float* ln5s= (const float*)d_in[28]; const float* ln5b= (const float*)d_in[29];
    const float* ln6s= (const float*)d_in[30]; const float* ln6b= (const float*)d_in[31];

    const int BN  = 8 * 128;                 // 1024 node rows
    const long long BNN = 8LL * 128 * 128;   // 131072 edge rows

    float* ws  = (float*)d_ws;
    float* x1  = ws;
    float* q   = x1 + BN * CDIM;
    float* k   = q  + BN * CDIM;
    float* v   = k  + BN * CDIM;
    float* agg = v  + BN * CDIM;
    unsigned short* attn_bf = (unsigned short*)(agg + BN * CDIM);
    unsigned short* WeH = attn_bf + BNN * CDIM;
    unsigned short* WeL = WeH + 65536;
    unsigned short* WoH = WeL + 65536;
    unsigned short* W1H = WoH + 65536;
    unsigned short* W2H = W1H + 262144;

    float* xout = (float*)d_out;
    float* yout = xout + BN * CDIM;

    prep_all<<<2560, 256, 0, stream>>>(We, Woe, m2w1, m2w2, WeH, WeL, WoH, W1H, W2H);
    lnqkv_kernel<<<BN / 4, 256, 0, stream>>>(x, ln1s, ln1b, Wq, bq, Wk, bk, Wv, bv,
                                             x1, q, k, v);
    y_mega<<<(int)(BNN / MROWS), 512, 0, stream>>>(
        y, q, k, WeH, WeL, be, WoH, boe, W1H, m2b1, W2H, m2b2,
        ln4s, ln4b, ln6s, ln6b, attn_bf, yout);
    softmax_agg<<<BN, 256, 0, stream>>>(attn_bf, v, agg);
    x_path<<<BN / 4, 256, 0, stream>>>(x1, agg, Won, bon, ln3s, ln3b,
                                       m1w1, m1b1, m1w2, m1b2, ln5s, ln5b, xout);
}

// Round 3
// 923.403 us; speedup vs baseline: 1.0515x; 1.0320x over previous
//
#include <hip/hip_runtime.h>

#define CDIM 256
#define NSEQ 128
#define HID 1024
#define EPS 1e-5f
#define SCALE 0.17677669529663687f   // 1/sqrt(32)
#define MROWS 32

typedef __attribute__((ext_vector_type(8))) short short8;
typedef __attribute__((ext_vector_type(4))) float f32x4;

static __device__ __forceinline__ unsigned short f2bf(float x) {
    unsigned u = __float_as_uint(x);
    u += 0x7fff + ((u >> 16) & 1);          // RNE
    return (unsigned short)(u >> 16);
}
static __device__ __forceinline__ float bf2f(unsigned short h) {
    return __uint_as_float(((unsigned)h) << 16);
}
// pack two f32 -> two bf16 (RNE); low16 = cvt(a). Bit-identical to f2bf (r1/r2).
static __device__ __forceinline__ unsigned cvt_pk(float a, float b) {
    unsigned r;
    asm("v_cvt_pk_bf16_f32 %0, %1, %2" : "=v"(r) : "v"(a), "v"(b));
    return r;
}
static __device__ __forceinline__ unsigned short f2bf1(float x) {
    return (unsigned short)cvt_pk(x, x);   // 1 VALU op
}
static __device__ __forceinline__ float lo16f(unsigned u) { return __uint_as_float(u << 16); }
static __device__ __forceinline__ float hi16f(unsigned u) { return __uint_as_float(u & 0xffff0000u); }

// 16B-granule XOR swizzle (row stride 512 B ≡ 0 mod 128 B bank cycle).
// swz({r, r+4, r+8, r+12}) pairwise distinct for all r -> epilogue b16 stores
// from the 4 quads land in 4 distinct granule slots (conflict-free).
static __device__ __forceinline__ int swz(int row) { return (row ^ (row >> 2)) & 7; }
// LDS plane index for [32][256]-short plane, column c of row, swizzled.
static __device__ __forceinline__ int sidx(int row, int c) {
    return row * 256 + (((c >> 3) ^ swz(row)) << 3) + (c & 7);
}

// ---------------------------------------------------------------------------
// One launch: split/swizzle all 4 y-path weights into MFMA B-fragment order.
__global__ __launch_bounds__(256) void prep_all(
    const float* __restrict__ We, const float* __restrict__ Woe,
    const float* __restrict__ W1, const float* __restrict__ W2,
    unsigned short* __restrict__ WeH, unsigned short* __restrict__ WeL,
    unsigned short* __restrict__ WoH, unsigned short* __restrict__ W1H,
    unsigned short* __restrict__ W2H) {
    int blk = blockIdx.x;
    const float* W; unsigned short* H; unsigned short* L = nullptr;
    int N, ksBits, base;
    if (blk < 256)       { W = We;  H = WeH; L = WeL; N = 256;  ksBits = 3; base = 0; }
    else if (blk < 512)  { W = Woe; H = WoH; N = 256;  ksBits = 3; base = 256; }
    else if (blk < 1536) { W = W1;  H = W1H; N = 1024; ksBits = 3; base = 512; }
    else                 { W = W2;  H = W2H; N = 256;  ksBits = 5; base = 1536; }
    int idx = (blk - base) * 256 + threadIdx.x;
    int j = idx & 7, lane = (idx >> 3) & 63, rest = idx >> 9;
    int ks = rest & ((1 << ksBits) - 1), nt = rest >> ksBits;
    int n  = nt * 16 + (lane & 15);
    int kk = ks * 32 + ((lane >> 4) << 3) + j;
    float x = W[kk * N + n];
    unsigned short h = f2bf(x);
    H[idx] = h;
    if (L) L[idx] = f2bf(x - bf2f(h));
}

// ---------------------------------------------------------------------------
// Fused LN1 + qkv, 4 rows per block (weight values reused across 4 rows).
__global__ __launch_bounds__(256) void lnqkv_kernel(
    const float* __restrict__ x,
    const float* __restrict__ ln1s, const float* __restrict__ ln1b,
    const float* __restrict__ Wq, const float* __restrict__ bq,
    const float* __restrict__ Wk, const float* __restrict__ bk,
    const float* __restrict__ Wv, const float* __restrict__ bv,
    float* __restrict__ x1,
    float* __restrict__ q, float* __restrict__ k, float* __restrict__ v) {
    __shared__ float sX[4][CDIM];
    __shared__ float sMu[4], sRs[4];
    const int bi0 = blockIdx.x * 4, t = threadIdx.x;
    const int w = t >> 6, lane = t & 63;
    float xv[4];
    #pragma unroll
    for (int r = 0; r < 4; ++r) { xv[r] = x[(bi0 + r) * CDIM + t]; sX[r][t] = xv[r]; }
    __syncthreads();
    {
        float s = 0.f, ss = 0.f;
        #pragma unroll
        for (int m = 0; m < 4; ++m) { float a = sX[w][lane + 64 * m]; s += a; ss += a * a; }
        #pragma unroll
        for (int off = 32; off; off >>= 1) { s += __shfl_xor(s, off); ss += __shfl_xor(ss, off); }
        if (lane == 0) {
            float mu = s * (1.f / 256.f);
            sMu[w] = mu;
            sRs[w] = rsqrtf(ss * (1.f / 256.f) - mu * mu + EPS);
        }
    }
    __syncthreads();
    #pragma unroll
    for (int r = 0; r < 4; ++r) {
        float xn = (xv[r] - sMu[r]) * sRs[r] * ln1s[t] + ln1b[t];
        sX[r][t] = xn;
        x1[(bi0 + r) * CDIM + t] = xn;
    }
    __syncthreads();
    float aq[4], ak[4], av[4];
    #pragma unroll
    for (int r = 0; r < 4; ++r) { aq[r] = bq[t]; ak[r] = bk[t]; av[r] = bv[t]; }
    #pragma unroll 4
    for (int kk = 0; kk < CDIM; ++kk) {
        float wq = Wq[kk * CDIM + t], wk = Wk[kk * CDIM + t], wv = Wv[kk * CDIM + t];
        #pragma unroll
        for (int r = 0; r < 4; ++r) {
            float xd = sX[r][kk];
            aq[r] += xd * wq; ak[r] += xd * wk; av[r] += xd * wv;
        }
    }
    #pragma unroll
    for (int r = 0; r < 4; ++r) {
        q[(bi0 + r) * CDIM + t] = aq[r];
        k[(bi0 + r) * CDIM + t] = ak[r];
        v[(bi0 + r) * CDIM + t] = av[r];
    }
}

// ---------------------------------------------------------------------------
// bf16 split GEMM step over K=256: acc[mt][nt] += A*B.
// A planes: [32][256] shorts, 16B granules XOR-swizzled by swz(row).
// TERMS==3: Ah*Bh + Al*Bh + Ah*Bl ; TERMS==2: Ah*Bh + Al*Bh (B hi only).
template <int TERMS>
static __device__ __forceinline__ void gemmN(
    const unsigned short* Ah, const unsigned short* Al,
    const unsigned short* __restrict__ Bh, const unsigned short* __restrict__ Bl,
    int nt0, int ksTotal, int ks0, int lane, f32x4 acc[2][2])
{
    const int l16 = lane & 15, quad = lane >> 4;
    #pragma unroll 2
    for (int ks = 0; ks < 8; ++ks) {
        short8 bh[2], bl[2];
        #pragma unroll
        for (int nt = 0; nt < 2; ++nt) {
            size_t off = ((size_t)((nt0 + nt) * ksTotal + (ks0 + ks)) * 64 + lane) * 8;
            bh[nt] = *(const short8*)(Bh + off);
            if (TERMS == 3) bl[nt] = *(const short8*)(Bl + off);
        }
        #pragma unroll
        for (int mt = 0; mt < 2; ++mt) {
            const int row = mt * 16 + l16;
            const int ao  = row * 256 + (((ks * 4 + quad) ^ swz(row)) << 3);
            short8 ah = *(const short8*)(Ah + ao);
            short8 al = *(const short8*)(Al + ao);
            #pragma unroll
            for (int nt = 0; nt < 2; ++nt) {
                acc[mt][nt] = __builtin_amdgcn_mfma_f32_16x16x32_bf16(ah, bh[nt], acc[mt][nt], 0, 0, 0);
                acc[mt][nt] = __builtin_amdgcn_mfma_f32_16x16x32_bf16(al, bh[nt], acc[mt][nt], 0, 0, 0);
                if (TERMS == 3)
                    acc[mt][nt] = __builtin_amdgcn_mfma_f32_16x16x32_bf16(ah, bl[nt], acc[mt][nt], 0, 0, 0);
            }
        }
    }
}

// cross-wave row-LN for 32 rows (8 waves); mu in sSum[0..31], rs in sSS[0..31]
static __device__ __forceinline__ void ln_reduce32(
    float pre[2][2][4], float* sSum, float* sSS, int w, int l16, int quad, int tid)
{
    #pragma unroll
    for (int mt = 0; mt < 2; ++mt)
        #pragma unroll
        for (int r = 0; r < 4; ++r) {
            float s  = pre[mt][0][r] + pre[mt][1][r];
            float ss = pre[mt][0][r] * pre[mt][0][r] + pre[mt][1][r] * pre[mt][1][r];
            #pragma unroll
            for (int off = 1; off < 16; off <<= 1) {
                s  += __shfl_xor(s, off);
                ss += __shfl_xor(ss, off);
            }
            if (l16 == 0) {
                int row = mt * 16 + quad * 4 + r;
                sSum[w * 32 + row] = s;
                sSS [w * 32 + row] = ss;
            }
        }
    __syncthreads();
    if (tid < 32) {
        float S = 0.f, SS2 = 0.f;
        #pragma unroll
        for (int ww = 0; ww < 8; ++ww) { S += sSum[ww * 32 + tid]; SS2 += sSS[ww * 32 + tid]; }
        float mu = S * (1.f / 256.f);
        float rs = rsqrtf(SS2 * (1.f / 256.f) - mu * mu + EPS);
        sSum[tid] = mu; sSS[tid] = rs;
    }
    __syncthreads();
}

// ---------------------------------------------------------------------------
// Fused edge pipeline, M=32 rows/block, 512 threads (8 waves), 66 KB LDS
// -> 2 blocks/CU. Round-0 structure; planes in swizzled layout so the
// epilogue b16 stores from the 4 quads hit 4 distinct granule slots.
__global__ __launch_bounds__(512, 4) void y_mega(
    const float* __restrict__ y, const float* __restrict__ qg, const float* __restrict__ kg,
    const unsigned short* __restrict__ WeH, const unsigned short* __restrict__ WeL,
    const float* __restrict__ be,
    const unsigned short* __restrict__ WoH, const float* __restrict__ boe,
    const unsigned short* __restrict__ W1H, const float* __restrict__ b1,
    const unsigned short* __restrict__ W2H, const float* __restrict__ b2,
    const float* __restrict__ ln4s, const float* __restrict__ ln4b,
    const float* __restrict__ ln6s, const float* __restrict__ ln6b,
    unsigned short* __restrict__ attn_bf, float* __restrict__ yout)
{
    __shared__ __align__(16) unsigned short sAh[32 * 256], sAl[32 * 256];
    __shared__ __align__(16) unsigned short sHh[32 * 256], sHl[32 * 256];
    __shared__ float sSum[8 * 32], sSS[8 * 32];

    const int tid  = threadIdx.x;
    const int w    = tid >> 6, lane = tid & 63;
    const int l16  = lane & 15, quad = lane >> 4;
    const long long row0 = (long long)blockIdx.x * MROWS;
    const int b  = (int)(row0 >> 14);
    const int i  = (int)((row0 >> 7) & 127);
    const int j0 = (int)(row0 & 127);
    const float* qrow  = qg + ((b << 7) + i) * CDIM;
    const float* kbase = kg + ((b << 7) + j0) * CDIM;
    const int c0 = w * 32 + l16, c1 = c0 + 16;

    // ---- stage y tile as hi/lo bf16 planes (swizzled granules) ------------
    {
        const int r  = tid >> 4;                 // 32 rows, 16 threads/row
        const int cc = (tid & 15) * 16;
        const int fr = swz(r);
        const float* src = y + (row0 + r) * CDIM + cc;
        #pragma unroll
        for (int e = 0; e < 16; e += 8) {
            float4 v0 = *(const float4*)(src + e);
            float4 v1 = *(const float4*)(src + e + 4);
            unsigned h0 = cvt_pk(v0.x, v0.y);
            unsigned h1 = cvt_pk(v0.z, v0.w);
            unsigned h2 = cvt_pk(v1.x, v1.y);
            unsigned h3 = cvt_pk(v1.z, v1.w);
            unsigned L0 = cvt_pk(v0.x - lo16f(h0), v0.y - hi16f(h0));
            unsigned L1 = cvt_pk(v0.z - lo16f(h1), v0.w - hi16f(h1));
            unsigned L2 = cvt_pk(v1.x - lo16f(h2), v1.y - hi16f(h2));
            unsigned L3 = cvt_pk(v1.z - lo16f(h3), v1.w - hi16f(h3));
            const int gs = (((cc + e) >> 3) ^ fr);
            uint4 hv; hv.x = h0; hv.y = h1; hv.z = h2; hv.w = h3;
            uint4 lv; lv.x = L0; lv.y = L1; lv.z = L2; lv.w = L3;
            *(uint4*)&sAh[r * 256 + gs * 8] = hv;
            *(uint4*)&sAl[r * 256 + gs * 8] = lv;
        }
    }
    __syncthreads();

    f32x4 acc[2][2];
    const f32x4 zf = {0.f, 0.f, 0.f, 0.f};

    // ---- GEMM1 (3-term): e = y@We + be ------------------------------------
    #pragma unroll
    for (int mt = 0; mt < 2; ++mt) { acc[mt][0] = zf; acc[mt][1] = zf; }
    gemmN<3>(sAh, sAl, WeH, WeL, w * 2, 8, 0, lane, acc);

    float q0 = qrow[c0], q1 = qrow[c1];
    float be0 = be[c0], be1 = be[c1];
    float attnv[2][2][4];
    #pragma unroll
    for (int mt = 0; mt < 2; ++mt)
        #pragma unroll
        for (int r = 0; r < 4; ++r) {
            int mloc = mt * 16 + quad * 4 + r;
            float k0 = kbase[mloc * CDIM + c0], k1 = kbase[mloc * CDIM + c1];
            float e0 = acc[mt][0][r] + be0, e1 = acc[mt][1][r] + be1;
            float a0 = q0 * k0 * SCALE * ((e0 + 1.f) * e0);
            float a1 = q1 * k1 * SCALE * ((e1 + 1.f) * e1);
            attnv[mt][0][r] = a0; attnv[mt][1][r] = a1;
            attn_bf[(row0 + mloc) * CDIM + c0] = f2bf1(a0);
            attn_bf[(row0 + mloc) * CDIM + c1] = f2bf1(a1);
        }
    __syncthreads();                       // all waves done reading y planes

    #pragma unroll
    for (int mt = 0; mt < 2; ++mt)
        #pragma unroll
        for (int r = 0; r < 4; ++r) {
            int mloc = mt * 16 + quad * 4 + r;
            #pragma unroll
            for (int nt = 0; nt < 2; ++nt) {
                int c = (nt == 0) ? c0 : c1;
                float a = attnv[mt][nt][r];
                unsigned short h = f2bf1(a);
                const int ix = sidx(mloc, c);
                sAh[ix] = h;
                sAl[ix] = f2bf1(a - bf2f(h));
            }
        }
    __syncthreads();

    // ---- GEMM2 (2-term): edge = attn@Woe + boe ; y2 = LN4(edge + y) -------
    #pragma unroll
    for (int mt = 0; mt < 2; ++mt) { acc[mt][0] = zf; acc[mt][1] = zf; }
    gemmN<2>(sAh, sAl, WoH, nullptr, w * 2, 8, 0, lane, acc);

    float pre[2][2][4];
    float bo0 = boe[c0], bo1 = boe[c1];
    #pragma unroll
    for (int mt = 0; mt < 2; ++mt)
        #pragma unroll
        for (int r = 0; r < 4; ++r) {
            int mloc = mt * 16 + quad * 4 + r;
            pre[mt][0][r] = acc[mt][0][r] + bo0 + y[(row0 + mloc) * CDIM + c0];
            pre[mt][1][r] = acc[mt][1][r] + bo1 + y[(row0 + mloc) * CDIM + c1];
        }
    ln_reduce32(pre, sSum, sSS, w, l16, quad, tid);

    float l4s0 = ln4s[c0], l4b0 = ln4b[c0], l4s1 = ln4s[c1], l4b1 = ln4b[c1];
    float y2v[2][2][4];
    #pragma unroll
    for (int mt = 0; mt < 2; ++mt)
        #pragma unroll
        for (int r = 0; r < 4; ++r) {
            int mloc = mt * 16 + quad * 4 + r;
            float mu = sSum[mloc], rs = sSS[mloc];
            float v0 = (pre[mt][0][r] - mu) * rs * l4s0 + l4b0;
            float v1 = (pre[mt][1][r] - mu) * rs * l4s1 + l4b1;
            y2v[mt][0][r] = v0; y2v[mt][1][r] = v1;
            unsigned short h0 = f2bf1(v0), h1 = f2bf1(v1);
            const int i0 = sidx(mloc, c0), i1 = sidx(mloc, c1);
            sAh[i0] = h0; sAl[i0] = f2bf1(v0 - bf2f(h0));
            sAh[i1] = h1; sAl[i1] = f2bf1(v1 - bf2f(h1));
        }
    __syncthreads();                       // A planes now hold y2

    // ---- MLP (2-term), 4 quarters of 256 hidden units ---------------------
    f32x4 out[2][2];
    #pragma unroll
    for (int mt = 0; mt < 2; ++mt) { out[mt][0] = zf; out[mt][1] = zf; }
    for (int qq = 0; qq < 4; ++qq) {
        f32x4 hh[2][2];
        #pragma unroll
        for (int mt = 0; mt < 2; ++mt) { hh[mt][0] = zf; hh[mt][1] = zf; }
        gemmN<2>(sAh, sAl, W1H, nullptr, qq * 16 + w * 2, 8, 0, lane, hh);
        float bb0 = b1[qq * 256 + c0], bb1 = b1[qq * 256 + c1];
        __syncthreads();                   // previous fc2 done reading H planes
        #pragma unroll
        for (int mt = 0; mt < 2; ++mt)
            #pragma unroll
            for (int r = 0; r < 4; ++r) {
                int mloc = mt * 16 + quad * 4 + r;
                float h0 = fmaxf(hh[mt][0][r] + bb0, 0.f);
                float h1 = fmaxf(hh[mt][1][r] + bb1, 0.f);
                unsigned short hb0 = f2bf1(h0), hb1 = f2bf1(h1);
                const int i0 = sidx(mloc, c0), i1 = sidx(mloc, c1);
                sHh[i0] = hb0; sHl[i0] = f2bf1(h0 - bf2f(hb0));
                sHh[i1] = hb1; sHl[i1] = f2bf1(h1 - bf2f(hb1));
            }
        __syncthreads();
        gemmN<2>(sHh, sHl, W2H, nullptr, w * 2, 32, qq * 8, lane, out);
    }

    // ---- epilogue: y_out = LN6(y2 + mlp_out + b2) -------------------------
    float b20 = b2[c0], b21 = b2[c1];
    #pragma unroll
    for (int mt = 0; mt < 2; ++mt)
        #pragma unroll
        for (int r = 0; r < 4; ++r) {
            pre[mt][0][r] = y2v[mt][0][r] + out[mt][0][r] + b20;
            pre[mt][1][r] = y2v[mt][1][r] + out[mt][1][r] + b21;
        }
    ln_reduce32(pre, sSum, sSS, w, l16, quad, tid);

    float l6s0 = ln6s[c0], l6b0 = ln6b[c0], l6s1 = ln6s[c1], l6b1 = ln6b[c1];
    #pragma unroll
    for (int mt = 0; mt < 2; ++mt)
        #pragma unroll
        for (int r = 0; r < 4; ++r) {
            int mloc = mt * 16 + quad * 4 + r;
            float mu = sSum[mloc], rs = sSS[mloc];
            yout[(row0 + mloc) * CDIM + c0] = (pre[mt][0][r] - mu) * rs * l6s0 + l6b0;
            yout[(row0 + mloc) * CDIM + c1] = (pre[mt][1][r] - mu) * rs * l6s1 + l6b1;
        }
}

// ---------------------------------------------------------------------------
// softmax over j + weighted v-sum. 2 channels/thread, j-range split in 2 teams.
__global__ __launch_bounds__(256) void softmax_agg(
    const unsigned short* __restrict__ attn, const float* __restrict__ v,
    float* __restrict__ agg) {
    __shared__ float2 sM[2][128], sS[2][128], sO[2][128];
    const int bi = blockIdx.x, t = threadIdx.x;
    const int c2 = t & 127, team = t >> 7, ch = c2 * 2;
    const unsigned short* ap = attn + (size_t)bi * NSEQ * CDIM + ch;
    const float* vp = v + (size_t)(bi >> 7) * NSEQ * CDIM + ch;
    const int jb = team * 64;
    float m0 = -1e30f, m1 = -1e30f;
    #pragma unroll 4
    for (int j = jb; j < jb + 64; ++j) {
        unsigned uu = *(const unsigned*)(ap + (size_t)j * CDIM);
        m0 = fmaxf(m0, bf2f((unsigned short)uu));
        m1 = fmaxf(m1, bf2f((unsigned short)(uu >> 16)));
    }
    sM[team][c2] = make_float2(m0, m1);
    __syncthreads();
    float2 mo = sM[team ^ 1][c2];
    m0 = fmaxf(m0, mo.x); m1 = fmaxf(m1, mo.y);
    float s0 = 0.f, s1 = 0.f, o0 = 0.f, o1 = 0.f;
    #pragma unroll 4
    for (int j = jb; j < jb + 64; ++j) {
        unsigned uu = *(const unsigned*)(ap + (size_t)j * CDIM);
        float e0 = __expf(bf2f((unsigned short)uu) - m0);
        float e1 = __expf(bf2f((unsigned short)(uu >> 16)) - m1);
        float2 vv = *(const float2*)(vp + (size_t)j * CDIM);
        s0 += e0; s1 += e1;
        o0 += e0 * vv.x; o1 += e1 * vv.y;
    }
    sS[team][c2] = make_float2(s0, s1);
    sO[team][c2] = make_float2(o0, o1);
    __syncthreads();
    if (team == 0) {
        float2 s2 = sS[1][c2], o2 = sO[1][c2];
        float r0 = (o0 + o2.x) / (s0 + s2.x);
        float r1 = (o1 + o2.y) / (s1 + s2.y);
        *(float2*)(agg + (size_t)bi * CDIM + ch) = make_float2(r0, r1);
    }
}

// ---------------------------------------------------------------------------
// node path, 4 rows per block (weights reused across rows).
__global__ __launch_bounds__(256) void x_path(
    const float* __restrict__ x1, const float* __restrict__ agg,
    const float* __restrict__ Won, const float* __restrict__ bon,
    const float* __restrict__ ln3s, const float* __restrict__ ln3b,
    const float* __restrict__ w1, const float* __restrict__ b1,
    const float* __restrict__ w2, const float* __restrict__ b2,
    const float* __restrict__ ln5s, const float* __restrict__ ln5b,
    float* __restrict__ xout) {
    __shared__ float sG[4][CDIM];
    __shared__ float sP[4][CDIM];
    __shared__ float sH[4][HID];
    __shared__ float sMu[4], sRs[4];
    const int bi0 = blockIdx.x * 4, t = threadIdx.x;
    const int w = t >> 6, lane = t & 63;
    #pragma unroll
    for (int r = 0; r < 4; ++r) sG[r][t] = agg[(bi0 + r) * CDIM + t];
    __syncthreads();
    float no[4];
    #pragma unroll
    for (int r = 0; r < 4; ++r) no[r] = bon[t];
    #pragma unroll 4
    for (int kk = 0; kk < CDIM; ++kk) {
        float wv = Won[kk * CDIM + t];
        #pragma unroll
        for (int r = 0; r < 4; ++r) no[r] += sG[r][kk] * wv;
    }
    float pre[4];
    #pragma unroll
    for (int r = 0; r < 4; ++r) {
        pre[r] = x1[(bi0 + r) * CDIM + t] + no[r];
        sP[r][t] = pre[r];
    }
    __syncthreads();
    {
        float s = 0.f, ss = 0.f;
        #pragma unroll
        for (int m = 0; m < 4; ++m) { float a = sP[w][lane + 64 * m]; s += a; ss += a * a; }
        #pragma unroll
        for (int off = 32; off; off >>= 1) { s += __shfl_xor(s, off); ss += __shfl_xor(ss, off); }
        if (lane == 0) {
            float mu = s * (1.f / 256.f);
            sMu[w] = mu; sRs[w] = rsqrtf(ss * (1.f / 256.f) - mu * mu + EPS);
        }
    }
    __syncthreads();
    float x2[4];
    #pragma unroll
    for (int r = 0; r < 4; ++r) {
        x2[r] = (pre[r] - sMu[r]) * sRs[r] * ln3s[t] + ln3b[t];
        sP[r][t] = x2[r];
    }
    __syncthreads();
    float h[4][4];
    #pragma unroll
    for (int m = 0; m < 4; ++m) {
        float bb = b1[t + 256 * m];
        #pragma unroll
        for (int r = 0; r < 4; ++r) h[r][m] = bb;
    }
    #pragma unroll 2
    for (int kk = 0; kk < CDIM; ++kk) {
        float wv[4];
        #pragma unroll
        for (int m = 0; m < 4; ++m) wv[m] = w1[kk * HID + t + 256 * m];
        #pragma unroll
        for (int r = 0; r < 4; ++r) {
            float xd = sP[r][kk];
            #pragma unroll
            for (int m = 0; m < 4; ++m) h[r][m] += xd * wv[m];
        }
    }
    #pragma unroll
    for (int r = 0; r < 4; ++r)
        #pragma unroll
        for (int m = 0; m < 4; ++m) sH[r][t + 256 * m] = fmaxf(h[r][m], 0.f);
    __syncthreads();
    float o[4];
    #pragma unroll
    for (int r = 0; r < 4; ++r) o[r] = b2[t];
    #pragma unroll 4
    for (int u = 0; u < HID; ++u) {
        float wv = w2[u * CDIM + t];
        #pragma unroll
        for (int r = 0; r < 4; ++r) o[r] += sH[r][u] * wv;
    }
    float pre2[4];
    #pragma unroll
    for (int r = 0; r < 4; ++r) { pre2[r] = x2[r] + o[r]; sP[r][t] = pre2[r]; }
    __syncthreads();
    {
        float s = 0.f, ss = 0.f;
        #pragma unroll
        for (int m = 0; m < 4; ++m) { float a = sP[w][lane + 64 * m]; s += a; ss += a * a; }
        #pragma unroll
        for (int off = 32; off; off >>= 1) { s += __shfl_xor(s, off); ss += __shfl_xor(ss, off); }
        if (lane == 0) {
            float mu = s * (1.f / 256.f);
            sMu[w] = mu; sRs[w] = rsqrtf(ss * (1.f / 256.f) - mu * mu + EPS);
        }
    }
    __syncthreads();
    #pragma unroll
    for (int r = 0; r < 4; ++r)
        xout[(bi0 + r) * CDIM + t] = (pre2[r] - sMu[r]) * sRs[r] * ln5s[t] + ln5b[t];
}

// ---------------------------------------------------------------------------
extern "C" void kernel_launch(void* const* d_in, const int* in_sizes, int n_in,
                              void* d_out, int out_size, void* d_ws, size_t ws_size,
                              hipStream_t stream) {
    const float* x   = (const float*)d_in[0];
    const float* y   = (const float*)d_in[1];
    const float* Wq  = (const float*)d_in[2];  const float* bq  = (const float*)d_in[3];
    const float* Wk  = (const float*)d_in[4];  const float* bk  = (const float*)d_in[5];
    const float* Wv  = (const float*)d_in[6];  const float* bv  = (const float*)d_in[7];
    const float* We  = (const float*)d_in[8];  const float* be  = (const float*)d_in[9];
    const float* Woe = (const float*)d_in[10]; const float* boe = (const float*)d_in[11];
    const float* Won = (const float*)d_in[12]; const float* bon = (const float*)d_in[13];
    const float* m1w1= (const float*)d_in[14]; const float* m1b1= (const float*)d_in[15];
    const float* m1w2= (const float*)d_in[16]; const float* m1b2= (const float*)d_in[17];
    const float* m2w1= (const float*)d_in[18]; const float* m2b1= (const float*)d_in[19];
    const float* m2w2= (const float*)d_in[20]; const float* m2b2= (const float*)d_in[21];
    const float* ln1s= (const float*)d_in[22]; const float* ln1b= (const float*)d_in[23];
    const float* ln3s= (const float*)d_in[24]; const float* ln3b= (const float*)d_in[25];
    const float* ln4s= (const float*)d_in[26]; const float* ln4b= (const float*)d_in[27];
    const float* ln5s= (const float*)d_in[28]; const float* ln5b= (const float*)d_in[29];
    const float* ln6s= (const float*)d_in[30]; const float* ln6b= (const float*)d_in[31];

    const int BN  = 8 * 128;                 // 1024 node rows
    const long long BNN = 8LL * 128 * 128;   // 131072 edge rows

    float* ws  = (float*)d_ws;
    float* x1  = ws;
    float* q   = x1 + BN * CDIM;
    float* k   = q  + BN * CDIM;
    float* v   = k  + BN * CDIM;
    float* agg = v  + BN * CDIM;
    unsigned short* attn_bf = (unsigned short*)(agg + BN * CDIM);
    unsigned short* WeH = attn_bf + BNN * CDIM;
    unsigned short* WeL = WeH + 65536;
    unsigned short* WoH = WeL + 65536;
    unsigned short* W1H = WoH + 65536;
    unsigned short* W2H = W1H + 262144;

    float* xout = (float*)d_out;
    float* yout = xout + BN * CDIM;

    prep_all<<<2560, 256, 0, stream>>>(We, Woe, m2w1, m2w2, WeH, WeL, WoH, W1H, W2H);
    lnqkv_kernel<<<BN / 4, 256, 0, stream>>>(x, ln1s, ln1b, Wq, bq, Wk, bk, Wv, bv,
                                             x1, q, k, v);
    y_mega<<<(int)(BNN / MROWS), 512, 0, stream>>>(
        y, q, k, WeH, WeL, be, WoH, boe, W1H, m2b1, W2H, m2b2,
        ln4s, ln4b, ln6s, ln6b, attn_bf, yout);
    softmax_agg<<<BN, 256, 0, stream>>>(attn_bf, v, agg);
    x_path<<<BN / 4, 256, 0, stream>>>(x1, agg, Won, bon, ln3s, ln3b,
                                       m1w1, m1b1, m1w2, m1b2, ln5s, ln5b, xout);
}

// Round 4
// 805.420 us; speedup vs baseline: 1.2056x; 1.1465x over previous
//
#include <hip/hip_runtime.h>

#define CDIM 256
#define NSEQ 128
#define HID 1024
#define EPS 1e-5f
#define SCALE 0.17677669529663687f   // 1/sqrt(32)
#define ASTR 264                     // LDS A-plane row stride (shorts)
#define MROWS 32

typedef __attribute__((ext_vector_type(8))) short short8;
typedef __attribute__((ext_vector_type(4))) float f32x4;

static __device__ __forceinline__ unsigned short f2bf(float x) {
    unsigned u = __float_as_uint(x);
    u += 0x7fff + ((u >> 16) & 1);          // RNE
    return (unsigned short)(u >> 16);
}
static __device__ __forceinline__ float bf2f(unsigned short h) {
    return __uint_as_float(((unsigned)h) << 16);
}

// ---------------------------------------------------------------------------
// One launch: split/swizzle all 4 y-path weights into MFMA B-fragment order.
// out[((nt*(K/32)+ks)*64+lane)*8+j] = W[ks*32+(lane>>4)*8+j][nt*16+(lane&15)]
__global__ __launch_bounds__(256) void prep_all(
    const float* __restrict__ We, const float* __restrict__ Woe,
    const float* __restrict__ W1, const float* __restrict__ W2,
    unsigned short* __restrict__ WeH, unsigned short* __restrict__ WeL,
    unsigned short* __restrict__ WoH, unsigned short* __restrict__ W1H,
    unsigned short* __restrict__ W2H) {
    int blk = blockIdx.x;
    const float* W; unsigned short* H; unsigned short* L = nullptr;
    int N, ksBits, base;
    if (blk < 256)       { W = We;  H = WeH; L = WeL; N = 256;  ksBits = 3; base = 0; }
    else if (blk < 512)  { W = Woe; H = WoH; N = 256;  ksBits = 3; base = 256; }
    else if (blk < 1536) { W = W1;  H = W1H; N = 1024; ksBits = 3; base = 512; }
    else                 { W = W2;  H = W2H; N = 256;  ksBits = 5; base = 1536; }
    int idx = (blk - base) * 256 + threadIdx.x;
    int j = idx & 7, lane = (idx >> 3) & 63, rest = idx >> 9;
    int ks = rest & ((1 << ksBits) - 1), nt = rest >> ksBits;
    int n  = nt * 16 + (lane & 15);
    int kk = ks * 32 + ((lane >> 4) << 3) + j;
    float x = W[kk * N + n];
    unsigned short h = f2bf(x);
    H[idx] = h;
    if (L) L[idx] = f2bf(x - bf2f(h));
}

// ---------------------------------------------------------------------------
// Fused LN1 + qkv, 4 rows per block (weight values reused across 4 rows).
__global__ __launch_bounds__(256) void lnqkv_kernel(
    const float* __restrict__ x,
    const float* __restrict__ ln1s, const float* __restrict__ ln1b,
    const float* __restrict__ Wq, const float* __restrict__ bq,
    const float* __restrict__ Wk, const float* __restrict__ bk,
    const float* __restrict__ Wv, const float* __restrict__ bv,
    float* __restrict__ x1,
    float* __restrict__ q, float* __restrict__ k, float* __restrict__ v) {
    __shared__ float sX[4][CDIM];
    __shared__ float sMu[4], sRs[4];
    const int bi0 = blockIdx.x * 4, t = threadIdx.x;
    const int w = t >> 6, lane = t & 63;
    float xv[4];
    #pragma unroll
    for (int r = 0; r < 4; ++r) { xv[r] = x[(bi0 + r) * CDIM + t]; sX[r][t] = xv[r]; }
    __syncthreads();
    {   // wave w does LN stats for row w
        float s = 0.f, ss = 0.f;
        #pragma unroll
        for (int m = 0; m < 4; ++m) { float a = sX[w][lane + 64 * m]; s += a; ss += a * a; }
        #pragma unroll
        for (int off = 32; off; off >>= 1) { s += __shfl_xor(s, off); ss += __shfl_xor(ss, off); }
        if (lane == 0) {
            float mu = s * (1.f / 256.f);
            sMu[w] = mu;
            sRs[w] = rsqrtf(ss * (1.f / 256.f) - mu * mu + EPS);
        }
    }
    __syncthreads();
    #pragma unroll
    for (int r = 0; r < 4; ++r) {
        float xn = (xv[r] - sMu[r]) * sRs[r] * ln1s[t] + ln1b[t];
        sX[r][t] = xn;
        x1[(bi0 + r) * CDIM + t] = xn;
    }
    __syncthreads();
    float aq[4], ak[4], av[4];
    #pragma unroll
    for (int r = 0; r < 4; ++r) { aq[r] = bq[t]; ak[r] = bk[t]; av[r] = bv[t]; }
    #pragma unroll 4
    for (int kk = 0; kk < CDIM; ++kk) {
        float wq = Wq[kk * CDIM + t], wk = Wk[kk * CDIM + t], wv = Wv[kk * CDIM + t];
        #pragma unroll
        for (int r = 0; r < 4; ++r) {
            float xd = sX[r][kk];
            aq[r] += xd * wq; ak[r] += xd * wk; av[r] += xd * wv;
        }
    }
    #pragma unroll
    for (int r = 0; r < 4; ++r) {
        q[(bi0 + r) * CDIM + t] = aq[r];
        k[(bi0 + r) * CDIM + t] = ak[r];
        v[(bi0 + r) * CDIM + t] = av[r];
    }
}

// ---------------------------------------------------------------------------
// bf16 split GEMM step over K=256: acc[mt][nt] += A*B.
// TERMS==3: Ah*Bh + Al*Bh + Ah*Bl ; TERMS==2: Ah*Bh + Al*Bh (B hi only).
template <int TERMS>
static __device__ __forceinline__ void gemmN(
    const unsigned short* Ah, const unsigned short* Al,
    const unsigned short* __restrict__ Bh, const unsigned short* __restrict__ Bl,
    int nt0, int ksTotal, int ks0, int lane, f32x4 acc[2][2])
{
    const int l16 = lane & 15, quad = lane >> 4;
    #pragma unroll 2
    for (int ks = 0; ks < 8; ++ks) {
        short8 bh[2], bl[2];
        #pragma unroll
        for (int nt = 0; nt < 2; ++nt) {
            size_t off = ((size_t)((nt0 + nt) * ksTotal + (ks0 + ks)) * 64 + lane) * 8;
            bh[nt] = *(const short8*)(Bh + off);
            if (TERMS == 3) bl[nt] = *(const short8*)(Bl + off);
        }
        #pragma unroll
        for (int mt = 0; mt < 2; ++mt) {
            int ao = (mt * 16 + l16) * ASTR + ks * 32 + quad * 8;
            short8 ah = *(const short8*)(Ah + ao);
            short8 al = *(const short8*)(Al + ao);
            #pragma unroll
            for (int nt = 0; nt < 2; ++nt) {
                acc[mt][nt] = __builtin_amdgcn_mfma_f32_16x16x32_bf16(ah, bh[nt], acc[mt][nt], 0, 0, 0);
                acc[mt][nt] = __builtin_amdgcn_mfma_f32_16x16x32_bf16(al, bh[nt], acc[mt][nt], 0, 0, 0);
                if (TERMS == 3)
                    acc[mt][nt] = __builtin_amdgcn_mfma_f32_16x16x32_bf16(ah, bl[nt], acc[mt][nt], 0, 0, 0);
            }
        }
    }
}

// cross-wave row-LN for 32 rows; leaves mu in sSum[0..31], rs in sSS[0..31]
static __device__ __forceinline__ void ln_reduce32(
    float pre[2][2][4], float* sSum, float* sSS, int w, int l16, int quad, int tid)
{
    #pragma unroll
    for (int mt = 0; mt < 2; ++mt)
        #pragma unroll
        for (int r = 0; r < 4; ++r) {
            float s  = pre[mt][0][r] + pre[mt][1][r];
            float ss = pre[mt][0][r] * pre[mt][0][r] + pre[mt][1][r] * pre[mt][1][r];
            #pragma unroll
            for (int off = 1; off < 16; off <<= 1) {
                s  += __shfl_xor(s, off);
                ss += __shfl_xor(ss, off);
            }
            if (l16 == 0) {
                int row = mt * 16 + quad * 4 + r;
                sSum[w * 32 + row] = s;
                sSS [w * 32 + row] = ss;
            }
        }
    __syncthreads();
    if (tid < 32) {
        float S = 0.f, SS2 = 0.f;
        #pragma unroll
        for (int ww = 0; ww < 8; ++ww) { S += sSum[ww * 32 + tid]; SS2 += sSS[ww * 32 + tid]; }
        float mu = S * (1.f / 256.f);
        float rs = rsqrtf(SS2 * (1.f / 256.f) - mu * mu + EPS);
        sSum[tid] = mu; sSS[tid] = rs;
    }
    __syncthreads();
}

// ---------------------------------------------------------------------------
// Fused edge pipeline, M=32 rows/block, 512 threads (8 waves), ~70 KB LDS
// -> 2 blocks/CU. EXACT round-0 structure (441.8 µs) + per-tile softmax max
// (attnv is already in registers: 8 fmax + 4 shuffles + 1 store).
__global__ __launch_bounds__(512, 4) void y_mega(
    const float* __restrict__ y, const float* __restrict__ qg, const float* __restrict__ kg,
    const unsigned short* __restrict__ WeH, const unsigned short* __restrict__ WeL,
    const float* __restrict__ be,
    const unsigned short* __restrict__ WoH, const float* __restrict__ boe,
    const unsigned short* __restrict__ W1H, const float* __restrict__ b1,
    const unsigned short* __restrict__ W2H, const float* __restrict__ b2,
    const float* __restrict__ ln4s, const float* __restrict__ ln4b,
    const float* __restrict__ ln6s, const float* __restrict__ ln6b,
    unsigned short* __restrict__ attn_bf, float* __restrict__ pmax,
    float* __restrict__ yout)
{
    __shared__ unsigned short sAh[MROWS * ASTR], sAl[MROWS * ASTR];
    __shared__ unsigned short sHh[MROWS * ASTR], sHl[MROWS * ASTR];
    __shared__ float sSum[8 * 32], sSS[8 * 32];

    const int tid  = threadIdx.x;
    const int w    = tid >> 6, lane = tid & 63;
    const int l16  = lane & 15, quad = lane >> 4;
    const long long row0 = (long long)blockIdx.x * MROWS;
    const int b  = (int)(row0 >> 14);
    const int i  = (int)((row0 >> 7) & 127);
    const int j0 = (int)(row0 & 127);
    const float* qrow  = qg + ((b << 7) + i) * CDIM;
    const float* kbase = kg + ((b << 7) + j0) * CDIM;
    const int c0 = w * 32 + l16, c1 = c0 + 16;

    // ---- stage y tile as hi/lo bf16 planes --------------------------------
    {
        int r  = tid >> 4;                  // 32 rows, 16 threads/row
        int cc = (tid & 15) * 16;
        const float* src = y + (row0 + r) * CDIM + cc;
        unsigned short hbuf[16], lbuf[16];
        #pragma unroll
        for (int e = 0; e < 16; e += 4) {
            float4 vv = *(const float4*)(src + e);
            float a[4] = {vv.x, vv.y, vv.z, vv.w};
            #pragma unroll
            for (int d = 0; d < 4; ++d) {
                unsigned short h = f2bf(a[d]);
                hbuf[e + d] = h;
                lbuf[e + d] = f2bf(a[d] - bf2f(h));
            }
        }
        #pragma unroll
        for (int e = 0; e < 16; e += 8) {
            *(short8*)&sAh[r * ASTR + cc + e] = *(short8*)&hbuf[e];
            *(short8*)&sAl[r * ASTR + cc + e] = *(short8*)&lbuf[e];
        }
    }
    __syncthreads();

    f32x4 acc[2][2];
    const f32x4 zf = {0.f, 0.f, 0.f, 0.f};

    // ---- GEMM1 (3-term): e = y@We + be ------------------------------------
    #pragma unroll
    for (int mt = 0; mt < 2; ++mt) { acc[mt][0] = zf; acc[mt][1] = zf; }
    gemmN<3>(sAh, sAl, WeH, WeL, w * 2, 8, 0, lane, acc);

    float q0 = qrow[c0], q1 = qrow[c1];
    float be0 = be[c0], be1 = be[c1];
    float attnv[2][2][4];
    #pragma unroll
    for (int mt = 0; mt < 2; ++mt)
        #pragma unroll
        for (int r = 0; r < 4; ++r) {
            int mloc = mt * 16 + quad * 4 + r;
            float k0 = kbase[mloc * CDIM + c0], k1 = kbase[mloc * CDIM + c1];
            float e0 = acc[mt][0][r] + be0, e1 = acc[mt][1][r] + be1;
            float a0 = q0 * k0 * SCALE * ((e0 + 1.f) * e0);
            float a1 = q1 * k1 * SCALE * ((e1 + 1.f) * e1);
            attnv[mt][0][r] = a0; attnv[mt][1][r] = a1;
            attn_bf[(row0 + mloc) * CDIM + c0] = f2bf(a0);
            attn_bf[(row0 + mloc) * CDIM + c1] = f2bf(a1);
        }

    // ---- per-tile softmax max over the 32 j-rows (softmax is over j; this
    // block holds j0..j0+31 for fixed (b,i)). f32 max shift cancels exactly
    // in softmax, so no numerics change vs bf16 max.
    {
        float mx0 = -1e30f, mx1 = -1e30f;
        #pragma unroll
        for (int mt = 0; mt < 2; ++mt)
            #pragma unroll
            for (int r = 0; r < 4; ++r) {
                mx0 = fmaxf(mx0, attnv[mt][0][r]);
                mx1 = fmaxf(mx1, attnv[mt][1][r]);
            }
        mx0 = fmaxf(mx0, __shfl_xor(mx0, 16));
        mx0 = fmaxf(mx0, __shfl_xor(mx0, 32));
        mx1 = fmaxf(mx1, __shfl_xor(mx1, 16));
        mx1 = fmaxf(mx1, __shfl_xor(mx1, 32));
        if (quad == 0) {
            float* pm = pmax + ((size_t)((b << 7) + i) * 4 + (j0 >> 5)) * CDIM;
            pm[c0] = mx0;
            pm[c1] = mx1;
        }
    }
    __syncthreads();                       // all waves done reading y planes

    #pragma unroll
    for (int mt = 0; mt < 2; ++mt)
        #pragma unroll
        for (int r = 0; r < 4; ++r) {
            int mloc = mt * 16 + quad * 4 + r;
            #pragma unroll
            for (int nt = 0; nt < 2; ++nt) {
                int c = (nt == 0) ? c0 : c1;
                float a = attnv[mt][nt][r];
                unsigned short h = f2bf(a);
                sAh[mloc * ASTR + c] = h;
                sAl[mloc * ASTR + c] = f2bf(a - bf2f(h));
            }
        }
    __syncthreads();

    // ---- GEMM2 (2-term): edge = attn@Woe + boe ; y2 = LN4(edge + y) -------
    #pragma unroll
    for (int mt = 0; mt < 2; ++mt) { acc[mt][0] = zf; acc[mt][1] = zf; }
    gemmN<2>(sAh, sAl, WoH, nullptr, w * 2, 8, 0, lane, acc);

    float pre[2][2][4];
    float bo0 = boe[c0], bo1 = boe[c1];
    #pragma unroll
    for (int mt = 0; mt < 2; ++mt)
        #pragma unroll
        for (int r = 0; r < 4; ++r) {
            int mloc = mt * 16 + quad * 4 + r;
            pre[mt][0][r] = acc[mt][0][r] + bo0 + y[(row0 + mloc) * CDIM + c0];
            pre[mt][1][r] = acc[mt][1][r] + bo1 + y[(row0 + mloc) * CDIM + c1];
        }
    ln_reduce32(pre, sSum, sSS, w, l16, quad, tid);

    float l4s0 = ln4s[c0], l4b0 = ln4b[c0], l4s1 = ln4s[c1], l4b1 = ln4b[c1];
    float y2v[2][2][4];
    #pragma unroll
    for (int mt = 0; mt < 2; ++mt)
        #pragma unroll
        for (int r = 0; r < 4; ++r) {
            int mloc = mt * 16 + quad * 4 + r;
            float mu = sSum[mloc], rs = sSS[mloc];
            float v0 = (pre[mt][0][r] - mu) * rs * l4s0 + l4b0;
            float v1 = (pre[mt][1][r] - mu) * rs * l4s1 + l4b1;
            y2v[mt][0][r] = v0; y2v[mt][1][r] = v1;
            unsigned short h0 = f2bf(v0), h1 = f2bf(v1);
            sAh[mloc * ASTR + c0] = h0; sAl[mloc * ASTR + c0] = f2bf(v0 - bf2f(h0));
            sAh[mloc * ASTR + c1] = h1; sAl[mloc * ASTR + c1] = f2bf(v1 - bf2f(h1));
        }
    __syncthreads();                       // A planes now hold y2

    // ---- MLP (2-term), 4 quarters of 256 hidden units ---------------------
    f32x4 out[2][2];
    #pragma unroll
    for (int mt = 0; mt < 2; ++mt) { out[mt][0] = zf; out[mt][1] = zf; }
    for (int qq = 0; qq < 4; ++qq) {
        f32x4 hh[2][2];
        #pragma unroll
        for (int mt = 0; mt < 2; ++mt) { hh[mt][0] = zf; hh[mt][1] = zf; }
        gemmN<2>(sAh, sAl, W1H, nullptr, qq * 16 + w * 2, 8, 0, lane, hh);
        float bb0 = b1[qq * 256 + c0], bb1 = b1[qq * 256 + c1];
        __syncthreads();                   // previous fc2 done reading H planes
        #pragma unroll
        for (int mt = 0; mt < 2; ++mt)
            #pragma unroll
            for (int r = 0; r < 4; ++r) {
                int mloc = mt * 16 + quad * 4 + r;
                float h0 = fmaxf(hh[mt][0][r] + bb0, 0.f);
                float h1 = fmaxf(hh[mt][1][r] + bb1, 0.f);
                unsigned short hb0 = f2bf(h0), hb1 = f2bf(h1);
                sHh[mloc * ASTR + c0] = hb0; sHl[mloc * ASTR + c0] = f2bf(h0 - bf2f(hb0));
                sHh[mloc * ASTR + c1] = hb1; sHl[mloc * ASTR + c1] = f2bf(h1 - bf2f(hb1));
            }
        __syncthreads();
        gemmN<2>(sHh, sHl, W2H, nullptr, w * 2, 32, qq * 8, lane, out);
    }

    // ---- epilogue: y_out = LN6(y2 + mlp_out + b2) -------------------------
    float b20 = b2[c0], b21 = b2[c1];
    #pragma unroll
    for (int mt = 0; mt < 2; ++mt)
        #pragma unroll
        for (int r = 0; r < 4; ++r) {
            pre[mt][0][r] = y2v[mt][0][r] + out[mt][0][r] + b20;
            pre[mt][1][r] = y2v[mt][1][r] + out[mt][1][r] + b21;
        }
    ln_reduce32(pre, sSum, sSS, w, l16, quad, tid);

    float l6s0 = ln6s[c0], l6b0 = ln6b[c0], l6s1 = ln6s[c1], l6b1 = ln6b[c1];
    #pragma unroll
    for (int mt = 0; mt < 2; ++mt)
        #pragma unroll
        for (int r = 0; r < 4; ++r) {
            int mloc = mt * 16 + quad * 4 + r;
            float mu = sSum[mloc], rs = sSS[mloc];
            yout[(row0 + mloc) * CDIM + c0] = (pre[mt][0][r] - mu) * rs * l6s0 + l6b0;
            yout[(row0 + mloc) * CDIM + c1] = (pre[mt][1][r] - mu) * rs * l6s1 + l6b1;
        }
}

// ---------------------------------------------------------------------------
// softmax over j + weighted v-sum, SINGLE pass: max comes precomputed from
// y_mega (4 partial maxes per (b,i,ch)). 2 channels/thread, j split in 2 teams.
__global__ __launch_bounds__(256) void softmax_agg(
    const unsigned short* __restrict__ attn, const float* __restrict__ v,
    const float* __restrict__ pmax, float* __restrict__ agg) {
    __shared__ float2 sS[2][128], sO[2][128];
    const int bi = blockIdx.x, t = threadIdx.x;
    const int c2 = t & 127, team = t >> 7, ch = c2 * 2;
    const unsigned short* ap = attn + (size_t)bi * NSEQ * CDIM + ch;
    const float* vp = v + (size_t)(bi >> 7) * NSEQ * CDIM + ch;
    const float* mp = pmax + (size_t)bi * 4 * CDIM + ch;
    float2 mv0 = *(const float2*)(mp);
    float2 mv1 = *(const float2*)(mp + CDIM);
    float2 mv2 = *(const float2*)(mp + 2 * CDIM);
    float2 mv3 = *(const float2*)(mp + 3 * CDIM);
    float m0 = fmaxf(fmaxf(mv0.x, mv1.x), fmaxf(mv2.x, mv3.x));
    float m1 = fmaxf(fmaxf(mv0.y, mv1.y), fmaxf(mv2.y, mv3.y));
    const int jb = team * 64;
    float s0 = 0.f, s1 = 0.f, o0 = 0.f, o1 = 0.f;
    #pragma unroll 8
    for (int j = jb; j < jb + 64; ++j) {
        unsigned uu = *(const unsigned*)(ap + (size_t)j * CDIM);
        float e0 = __expf(bf2f((unsigned short)uu) - m0);
        float e1 = __expf(bf2f((unsigned short)(uu >> 16)) - m1);
        float2 vv = *(const float2*)(vp + (size_t)j * CDIM);
        s0 += e0; s1 += e1;
        o0 += e0 * vv.x; o1 += e1 * vv.y;
    }
    sS[team][c2] = make_float2(s0, s1);
    sO[team][c2] = make_float2(o0, o1);
    __syncthreads();
    if (team == 0) {
        float2 s2 = sS[1][c2], o2 = sO[1][c2];
        float r0 = (o0 + o2.x) / (s0 + s2.x);
        float r1 = (o1 + o2.y) / (s1 + s2.y);
        *(float2*)(agg + (size_t)bi * CDIM + ch) = make_float2(r0, r1);
    }
}

// ---------------------------------------------------------------------------
// node path, 4 rows per block, 512 threads (8 waves): split-K over Won/fc2,
// 2 hidden units/thread for fc1. Same weight bytes, 2x latency hiding.
__global__ __launch_bounds__(512) void x_path(
    const float* __restrict__ x1, const float* __restrict__ agg,
    const float* __restrict__ Won, const float* __restrict__ bon,
    const float* __restrict__ ln3s, const float* __restrict__ ln3b,
    const float* __restrict__ w1, const float* __restrict__ b1,
    const float* __restrict__ w2, const float* __restrict__ b2,
    const float* __restrict__ ln5s, const float* __restrict__ ln5b,
    float* __restrict__ xout) {
    __shared__ float sG[4][CDIM];
    __shared__ float sP[4][CDIM];
    __shared__ float sH[4][HID];
    __shared__ float sR[2][4][CDIM];
    __shared__ float sMu[4], sRs[4];
    const int bi0 = blockIdx.x * 4, t = threadIdx.x;
    const int ct = t & 255, hs = t >> 8;
    const int w = t >> 6, lane = t & 63;
    #pragma unroll
    for (int p = 0; p < 2; ++p) {
        int idx = p * 512 + t;
        ((float*)sG)[idx] = agg[bi0 * CDIM + idx];
    }
    __syncthreads();
    // node GEMM, split-k halves
    float no[4] = {0.f, 0.f, 0.f, 0.f};
    const int k0 = hs * 128;
    #pragma unroll 4
    for (int kk = k0; kk < k0 + 128; ++kk) {
        float wv = Won[kk * CDIM + ct];
        #pragma unroll
        for (int r = 0; r < 4; ++r) no[r] += sG[r][kk] * wv;
    }
    #pragma unroll
    for (int r = 0; r < 4; ++r) sR[hs][r][ct] = no[r];
    __syncthreads();
    float pre[4];
    #pragma unroll
    for (int r = 0; r < 4; ++r) {
        pre[r] = x1[(bi0 + r) * CDIM + ct] + bon[ct] + sR[0][r][ct] + sR[1][r][ct];
        if (hs == 0) sP[r][ct] = pre[r];
    }
    __syncthreads();
    if (w < 4) {   // waves 0-3: LN stats for rows 0-3
        float s = 0.f, ss = 0.f;
        #pragma unroll
        for (int m = 0; m < 4; ++m) { float a = sP[w][lane + 64 * m]; s += a; ss += a * a; }
        #pragma unroll
        for (int off = 32; off; off >>= 1) { s += __shfl_xor(s, off); ss += __shfl_xor(ss, off); }
        if (lane == 0) {
            float mu = s * (1.f / 256.f);
            sMu[w] = mu; sRs[w] = rsqrtf(ss * (1.f / 256.f) - mu * mu + EPS);
        }
    }
    __syncthreads();
    float x2[4];
    #pragma unroll
    for (int r = 0; r < 4; ++r) {
        x2[r] = (pre[r] - sMu[r]) * sRs[r] * ln3s[ct] + ln3b[ct];
        if (hs == 0) sP[r][ct] = x2[r];
    }
    __syncthreads();
    // fc1: 2 hidden units per thread (t, t+512)
    float h0[4], h1[4];
    {
        float bb0 = b1[t], bb1 = b1[t + 512];
        #pragma unroll
        for (int r = 0; r < 4; ++r) { h0[r] = bb0; h1[r] = bb1; }
    }
    #pragma unroll 2
    for (int kk = 0; kk < CDIM; ++kk) {
        float wv0 = w1[kk * HID + t], wv1 = w1[kk * HID + t + 512];
        #pragma unroll
        for (int r = 0; r < 4; ++r) {
            float xd = sP[r][kk];
            h0[r] += xd * wv0; h1[r] += xd * wv1;
        }
    }
    #pragma unroll
    for (int r = 0; r < 4; ++r) {
        sH[r][t]       = fmaxf(h0[r], 0.f);
        sH[r][t + 512] = fmaxf(h1[r], 0.f);
    }
    __syncthreads();
    // fc2, split-u halves
    float o[4] = {0.f, 0.f, 0.f, 0.f};
    const int u0 = hs * 512;
    #pragma unroll 4
    for (int u = u0; u < u0 + 512; ++u) {
        float wv = w2[u * CDIM + ct];
        #pragma unroll
        for (int r = 0; r < 4; ++r) o[r] += sH[r][u] * wv;
    }
    #pragma unroll
    for (int r = 0; r < 4; ++r) sR[hs][r][ct] = o[r];
    __syncthreads();
    float pre2[4];
    #pragma unroll
    for (int r = 0; r < 4; ++r) {
        pre2[r] = x2[r] + b2[ct] + sR[0][r][ct] + sR[1][r][ct];
        if (hs == 0) sP[r][ct] = pre2[r];
    }
    __syncthreads();
    if (w < 4) {
        float s = 0.f, ss = 0.f;
        #pragma unroll
        for (int m = 0; m < 4; ++m) { float a = sP[w][lane + 64 * m]; s += a; ss += a * a; }
        #pragma unroll
        for (int off = 32; off; off >>= 1) { s += __shfl_xor(s, off); ss += __shfl_xor(ss, off); }
        if (lane == 0) {
            float mu = s * (1.f / 256.f);
            sMu[w] = mu; sRs[w] = rsqrtf(ss * (1.f / 256.f) - mu * mu + EPS);
        }
    }
    __syncthreads();
    if (hs == 0)
        #pragma unroll
        for (int r = 0; r < 4; ++r)
            xout[(bi0 + r) * CDIM + ct] = (pre2[r] - sMu[r]) * sRs[r] * ln5s[ct] + ln5b[ct];
}

// ---------------------------------------------------------------------------
extern "C" void kernel_launch(void* const* d_in, const int* in_sizes, int n_in,
                              void* d_out, int out_size, void* d_ws, size_t ws_size,
                              hipStream_t stream) {
    const float* x   = (const float*)d_in[0];
    const float* y   = (const float*)d_in[1];
    const float* Wq  = (const float*)d_in[2];  const float* bq  = (const float*)d_in[3];
    const float* Wk  = (const float*)d_in[4];  const float* bk  = (const float*)d_in[5];
    const float* Wv  = (const float*)d_in[6];  const float* bv  = (const float*)d_in[7];
    const float* We  = (const float*)d_in[8];  const float* be  = (const float*)d_in[9];
    const float* Woe = (const float*)d_in[10]; const float* boe = (const float*)d_in[11];
    const float* Won = (const float*)d_in[12]; const float* bon = (const float*)d_in[13];
    const float* m1w1= (const float*)d_in[14]; const float* m1b1= (const float*)d_in[15];
    const float* m1w2= (const float*)d_in[16]; const float* m1b2= (const float*)d_in[17];
    const float* m2w1= (const float*)d_in[18]; const float* m2b1= (const float*)d_in[19];
    const float* m2w2= (const float*)d_in[20]; const float* m2b2= (const float*)d_in[21];
    const float* ln1s= (const float*)d_in[22]; const float* ln1b= (const float*)d_in[23];
    const float* ln3s= (const float*)d_in[24]; const float* ln3b= (const float*)d_in[25];
    const float* ln4s= (const float*)d_in[26]; const float* ln4b= (const float*)d_in[27];
    const float* ln5s= (const float*)d_in[28]; const float* ln5b= (const float*)d_in[29];
    const float* ln6s= (const float*)d_in[30]; const float* ln6b= (const float*)d_in[31];

    const int BN  = 8 * 128;                 // 1024 node rows
    const long long BNN = 8LL * 128 * 128;   // 131072 edge rows

    float* ws  = (float*)d_ws;
    float* x1  = ws;
    float* q   = x1 + BN * CDIM;
    float* k   = q  + BN * CDIM;
    float* v   = k  + BN * CDIM;
    float* agg = v  + BN * CDIM;
    unsigned short* attn_bf = (unsigned short*)(agg + BN * CDIM);
    unsigned short* WeH = attn_bf + BNN * CDIM;
    unsigned short* WeL = WeH + 65536;
    unsigned short* WoH = WeL + 65536;
    unsigned short* W1H = WoH + 65536;
    unsigned short* W2H = W1H + 262144;
    float* pmax = (float*)(W2H + 262144);    // 1024 * 4 * 256 f32 = 4 MiB

    float* xout = (float*)d_out;
    float* yout = xout + BN * CDIM;

    prep_all<<<2560, 256, 0, stream>>>(We, Woe, m2w1, m2w2, WeH, WeL, WoH, W1H, W2H);
    lnqkv_kernel<<<BN / 4, 256, 0, stream>>>(x, ln1s, ln1b, Wq, bq, Wk, bk, Wv, bv,
                                             x1, q, k, v);
    y_mega<<<(int)(BNN / MROWS), 512, 0, stream>>>(
        y, q, k, WeH, WeL, be, WoH, boe, W1H, m2b1, W2H, m2b2,
        ln4s, ln4b, ln6s, ln6b, attn_bf, pmax, yout);
    softmax_agg<<<BN, 256, 0, stream>>>(attn_bf, v, pmax, agg);
    x_path<<<BN / 4, 512, 0, stream>>>(x1, agg, Won, bon, ln3s, ln3b,
                                       m1w1, m1b1, m1w2, m1b2, ln5s, ln5b, xout);
}